// Round 1
// baseline (686.527 us; speedup 1.0000x reference)
//
#include <hip/hip_runtime.h>
#include <hip/hip_bf16.h>
#include <math.h>

#define HH 512
#define WW 512
#define BB 8
#define TT 5
#define MID 16
#define HWSZ (HH*WW)      /* 262144 = 2^18 */
#define NPIX (BB*HWSZ)    /* 2097152 */

// ---------- bf16 helpers ----------
__device__ inline unsigned short f2bf(float f){
  unsigned u = __float_as_uint(f);
  u = u + 0x7fffu + ((u >> 16) & 1u);     // round-to-nearest-even
  return (unsigned short)(u >> 16);
}
__device__ inline float blo(unsigned u){ return __uint_as_float(u << 16); }
__device__ inline float bhi(unsigned u){ return __uint_as_float(u & 0xffff0000u); }

// ---------- consts layout (floats, offset from ws+64) ----------
// [0] mean  [1] inv_std
// [2..145]   w1eff[16][9]  (summed over T)
// [146..161] sc1   [162..177] bi1
// [178..193] sc2   [194..209] bi2
// [210..225] sc3   [226..241] bi3
// [256..2559]  w2t[tap][in][out]  (2304)
// [2560..4863] w3t[tap][in][out]  (2304)

// ================= kernel 1: accumulate |raw_diff| + stats =================
__global__ __launch_bounds__(256) void k_acc(const float* __restrict__ rd,
                                             float* __restrict__ acc,
                                             double* __restrict__ stats){
  int i = blockIdx.x * 256 + threadIdx.x;
  int b = i >> 18, p = i & (HWSZ - 1);
  const float* base = rd + (size_t)b * 4 * HWSZ + p;
  float s = fabsf(base[0]) + fabsf(base[HWSZ]) + fabsf(base[2*HWSZ]) + fabsf(base[3*HWSZ]);
  acc[i] = s;
  float s2 = s * s;
  #pragma unroll
  for (int off = 32; off; off >>= 1){
    s  += __shfl_down(s,  off);
    s2 += __shfl_down(s2, off);
  }
  __shared__ float ls[4], ls2[4];
  int lane = threadIdx.x & 63, wid = threadIdx.x >> 6;
  if (lane == 0){ ls[wid] = s; ls2[wid] = s2; }
  __syncthreads();
  if (threadIdx.x == 0){
    float a = ls[0]+ls[1]+ls[2]+ls[3];
    float a2 = ls2[0]+ls2[1]+ls2[2]+ls2[3];
    atomicAdd(stats,     (double)a);
    atomicAdd(stats + 1, (double)a2);
  }
}

// ================= kernel 2: precompute scalars / folded weights =================
__global__ __launch_bounds__(256) void k_prep(const double* __restrict__ stats,
    const float* __restrict__ w1, const float* __restrict__ w2, const float* __restrict__ w3,
    const float* __restrict__ g1, const float* __restrict__ b1, const float* __restrict__ rm1, const float* __restrict__ rv1,
    const float* __restrict__ g2, const float* __restrict__ b2, const float* __restrict__ rm2, const float* __restrict__ rv2,
    const float* __restrict__ g3, const float* __restrict__ b3, const float* __restrict__ rm3, const float* __restrict__ rv3,
    float* __restrict__ cst){
  int t = threadIdx.x;
  if (t == 0){
    double n = (double)NPIX;
    double mean = stats[0] / n;
    double var  = (stats[1] - n * mean * mean) / (n - 1.0);
    double sd   = sqrt(var);
    cst[0] = (float)mean;
    cst[1] = (float)(1.0 / (sd + 1e-6));
  }
  if (t < 144){
    int c = t / 9, k = t % 9;
    float s = 0.f;
    for (int f = 0; f < TT; f++) s += w1[c*45 + f*9 + k];
    cst[2 + t] = s;
  }
  if (t < 16){
    float s1 = g1[t] * rsqrtf(rv1[t] + 1e-5f);
    cst[146 + t] = s1; cst[162 + t] = b1[t] - rm1[t] * s1;
    float s2 = g2[t] * rsqrtf(rv2[t] + 1e-5f);
    cst[178 + t] = s2; cst[194 + t] = b2[t] - rm2[t] * s2;
    float s3 = g3[t] * rsqrtf(rv3[t] + 1e-5f);
    cst[210 + t] = s3; cst[226 + t] = b3[t] - rm3[t] * s3;
  }
  // transpose w2/w3: [o][i][k] -> [k][i][o] for contiguous uniform (scalar) loads
  for (int it = 0; it < 9; it++){
    int idx = it * 256 + t;                 // < 2304
    int k = idx >> 8, rem = idx & 255, ii = rem >> 4, oo = rem & 15;
    cst[256  + idx] = w2[oo*144 + ii*9 + k];
    cst[2560 + idx] = w3[oo*144 + ii*9 + k];
  }
}

// ================= kernel 3: conv1 (1->16ch, dil 1) + BN + ReLU =================
__global__ __launch_bounds__(256) void k_conv1(const float* __restrict__ acc,
                                               const float* __restrict__ C,
                                               uint4* __restrict__ h1){
  int i = blockIdx.x * 256 + threadIdx.x;
  int b = i >> 18, p = i & (HWSZ - 1);
  int y = p >> 9, x = p & 511;
  float mean = C[0], inv = C[1];
  const float* ab = acc + ((size_t)b << 18);
  float a[MID];
  #pragma unroll
  for (int o = 0; o < MID; o++) a[o] = 0.f;
  #pragma unroll
  for (int ky = 0; ky < 3; ky++){
    int yy = y + ky - 1;
    if ((unsigned)yy >= HH) continue;
    #pragma unroll
    for (int kx = 0; kx < 3; kx++){
      int xx = x + kx - 1;
      if ((unsigned)xx >= WW) continue;
      float m = (ab[(yy << 9) + xx] - mean) * inv;
      int k = ky * 3 + kx;
      #pragma unroll
      for (int o = 0; o < MID; o++) a[o] = fmaf(C[2 + o*9 + k], m, a[o]);
    }
  }
  unsigned pk[8];
  #pragma unroll
  for (int j = 0; j < 8; j++){
    float v0 = fmaxf(0.f, fmaf(a[2*j],   C[146 + 2*j],   C[162 + 2*j]));
    float v1 = fmaxf(0.f, fmaf(a[2*j+1], C[146 + 2*j+1], C[162 + 2*j+1]));
    pk[j] = (unsigned)f2bf(v0) | ((unsigned)f2bf(v1) << 16);
  }
  uint4* dst = h1 + (size_t)i * 2;
  dst[0] = make_uint4(pk[0], pk[1], pk[2], pk[3]);
  dst[1] = make_uint4(pk[4], pk[5], pk[6], pk[7]);
}

// ---------- shared 16x16x9 dilated conv body (bf16 NHWC16 input) ----------
template<int DIL>
__device__ inline void conv16(const uint4* __restrict__ hin, const float* __restrict__ wt,
                              int b, int y, int x, float a[MID]){
  #pragma unroll
  for (int ky = 0; ky < 3; ky++){
    int yy = y + (ky - 1) * DIL;
    if ((unsigned)yy >= HH) continue;
    #pragma unroll
    for (int kx = 0; kx < 3; kx++){
      int xx = x + (kx - 1) * DIL;
      if ((unsigned)xx >= WW) continue;
      const uint4* ptr = hin + ((((size_t)(b << 18)) | (unsigned)((yy << 9) + xx)) << 1);
      uint4 u0 = ptr[0], u1 = ptr[1];
      unsigned uu[8] = {u0.x,u0.y,u0.z,u0.w,u1.x,u1.y,u1.z,u1.w};
      float in[MID];
      #pragma unroll
      for (int j = 0; j < 8; j++){ in[2*j] = blo(uu[j]); in[2*j+1] = bhi(uu[j]); }
      const float* wk = wt + (ky*3 + kx) * 256;
      #pragma unroll
      for (int ii = 0; ii < MID; ii++){
        #pragma unroll
        for (int o = 0; o < MID; o++)
          a[o] = fmaf(wk[ii*16 + o], in[ii], a[o]);
      }
    }
  }
}

// ================= kernel 4: conv2 (16->16, dil 2) + BN + ReLU =================
__global__ __launch_bounds__(256) void k_conv2(const uint4* __restrict__ h1,
                                               const float* __restrict__ C,
                                               uint4* __restrict__ h2){
  int i = blockIdx.x * 256 + threadIdx.x;
  int b = i >> 18, p = i & (HWSZ - 1);
  int y = p >> 9, x = p & 511;
  float a[MID];
  #pragma unroll
  for (int o = 0; o < MID; o++) a[o] = 0.f;
  conv16<2>(h1, C + 256, b, y, x, a);
  unsigned pk[8];
  #pragma unroll
  for (int j = 0; j < 8; j++){
    float v0 = fmaxf(0.f, fmaf(a[2*j],   C[178 + 2*j],   C[194 + 2*j]));
    float v1 = fmaxf(0.f, fmaf(a[2*j+1], C[178 + 2*j+1], C[194 + 2*j+1]));
    pk[j] = (unsigned)f2bf(v0) | ((unsigned)f2bf(v1) << 16);
  }
  uint4* dst = h2 + (size_t)i * 2;
  dst[0] = make_uint4(pk[0], pk[1], pk[2], pk[3]);
  dst[1] = make_uint4(pk[4], pk[5], pk[6], pk[7]);
}

// ======== kernel 5: conv3 (dil 4) + BN + ReLU + 1x1 w4 + sigmoid + enhance ========
__global__ __launch_bounds__(256) void k_conv3f(const uint4* __restrict__ h2,
                                                const float* __restrict__ C,
                                                const float* __restrict__ w4,
                                                const float* __restrict__ bias,
                                                const float* __restrict__ xal,
                                                float* __restrict__ out){
  int i = blockIdx.x * 256 + threadIdx.x;
  int b = i >> 18, p = i & (HWSZ - 1);
  int y = p >> 9, x = p & 511;
  float a[MID];
  #pragma unroll
  for (int o = 0; o < MID; o++) a[o] = 0.f;
  conv16<4>(h2, C + 2560, b, y, x, a);
  float h3[MID];
  #pragma unroll
  for (int o = 0; o < MID; o++)
    h3[o] = fmaxf(0.f, fmaf(a[o], C[210 + o], C[226 + o]));

  float bs = bias[0];
  #pragma unroll
  for (int t = 0; t < TT; t++){
    const float* xb = xal + ((size_t)(b * TT + t) << 18);
    float r[9];
    #pragma unroll
    for (int k = 0; k < 9; k++){
      const float* wr = w4 + (t*9 + k) * 16;
      float s = 0.f;
      #pragma unroll
      for (int ii = 0; ii < MID; ii++) s = fmaf(wr[ii], h3[ii], s);
      r[k] = s;
    }
    float ov = 0.f;
    #pragma unroll
    for (int ky = 0; ky < 3; ky++){
      #pragma unroll
      for (int kx = 0; kx < 3; kx++){
        int k = ky*3 + kx;
        int yy = y + ky - 1, xx = x + kx - 1;
        float xv = ((unsigned)yy < HH && (unsigned)xx < WW) ? xb[(yy << 9) + xx] : 0.f;
        float z = r[k] + bs;
        float kern = fmaf(10.f, __frcp_rn(1.f + __expf(-z)), 0.1f);
        ov = fmaf(kern, xv, ov);
      }
    }
    out[(((size_t)(b * TT + t)) << 18) + p] = ov;
  }
}

extern "C" void kernel_launch(void* const* d_in, const int* in_sizes, int n_in,
                              void* d_out, int out_size, void* d_ws, size_t ws_size,
                              hipStream_t stream){
  const float* xal = (const float*)d_in[0];
  const float* rd  = (const float*)d_in[1];
  const float* w1  = (const float*)d_in[2];
  const float* g1  = (const float*)d_in[3];
  const float* b1  = (const float*)d_in[4];
  const float* rm1 = (const float*)d_in[5];
  const float* rv1 = (const float*)d_in[6];
  const float* w2  = (const float*)d_in[7];
  const float* g2  = (const float*)d_in[8];
  const float* b2  = (const float*)d_in[9];
  const float* rm2 = (const float*)d_in[10];
  const float* rv2 = (const float*)d_in[11];
  const float* w3  = (const float*)d_in[12];
  const float* g3  = (const float*)d_in[13];
  const float* b3  = (const float*)d_in[14];
  const float* rm3 = (const float*)d_in[15];
  const float* rv3 = (const float*)d_in[16];
  const float* w4  = (const float*)d_in[17];
  const float* bias= (const float*)d_in[18];
  float* out = (float*)d_out;

  char* ws = (char*)d_ws;
  double* stats = (double*)ws;                       // 16 B
  float*  cst   = (float*)(ws + 64);                 // ~19.5 KB
  float*  acc   = (float*)(ws + 32768);              // 8 MB
  uint4*  h1    = (uint4*)(ws + 32768 + (size_t)NPIX*4);                       // 64 MB (bf16 NHWC16)
  uint4*  h2    = (uint4*)(ws + 32768 + (size_t)NPIX*4 + (size_t)NPIX*32);     // 64 MB

  hipMemsetAsync(stats, 0, 64, stream);
  k_acc<<<NPIX/256, 256, 0, stream>>>(rd, acc, stats);
  k_prep<<<1, 256, 0, stream>>>(stats, w1, w2, w3,
                                g1, b1, rm1, rv1,
                                g2, b2, rm2, rv2,
                                g3, b3, rm3, rv3, cst);
  k_conv1<<<NPIX/256, 256, 0, stream>>>(acc, cst, h1);
  k_conv2<<<NPIX/256, 256, 0, stream>>>(h1, cst, h2);
  k_conv3f<<<NPIX/256, 256, 0, stream>>>(h2, cst, w4, bias, xal, out);
}

// Round 2
// 536.157 us; speedup vs baseline: 1.2805x; 1.2805x over previous
//
#include <hip/hip_runtime.h>
#include <hip/hip_bf16.h>
#include <math.h>

#define HH 512
#define WW 512
#define BB 8
#define TT 5
#define MID 16
#define HWSZ (HH*WW)      /* 262144 = 2^18 */
#define NPIX (BB*HWSZ)    /* 2097152 */

typedef __attribute__((ext_vector_type(8))) short bf16x8;
typedef __attribute__((ext_vector_type(4))) float f32x4;

// ---------- bf16 helpers ----------
__device__ inline unsigned short f2bf(float f){
  unsigned u = __float_as_uint(f);
  u = u + 0x7fffu + ((u >> 16) & 1u);     // round-to-nearest-even
  return (unsigned short)(u >> 16);
}
__device__ inline float blo(unsigned u){ return __uint_as_float(u << 16); }
__device__ inline float bhi(unsigned u){ return __uint_as_float(u & 0xffff0000u); }

union U4B { uint4 u; bf16x8 h; };

// ---------- consts layout (floats, offset from ws+64) ----------
// [0] mean  [1] inv_std
// [2..145]   w1eff[16][9]  (summed over T)
// [146..161] sc1   [162..177] bi1
// [178..193] sc2   [194..209] bi2
// [210..225] sc3   [226..241] bi3

// ================= kernel 1: accumulate |raw_diff| + stats =================
__global__ __launch_bounds__(256) void k_acc(const float* __restrict__ rd,
                                             float* __restrict__ acc,
                                             double* __restrict__ stats){
  int i = blockIdx.x * 256 + threadIdx.x;
  int b = i >> 18, p = i & (HWSZ - 1);
  const float* base = rd + (size_t)b * 4 * HWSZ + p;
  float s = fabsf(base[0]) + fabsf(base[HWSZ]) + fabsf(base[2*HWSZ]) + fabsf(base[3*HWSZ]);
  acc[i] = s;
  float s2 = s * s;
  #pragma unroll
  for (int off = 32; off; off >>= 1){
    s  += __shfl_down(s,  off);
    s2 += __shfl_down(s2, off);
  }
  __shared__ float ls[4], ls2[4];
  int lane = threadIdx.x & 63, wid = threadIdx.x >> 6;
  if (lane == 0){ ls[wid] = s; ls2[wid] = s2; }
  __syncthreads();
  if (threadIdx.x == 0){
    float a = ls[0]+ls[1]+ls[2]+ls[3];
    float a2 = ls2[0]+ls2[1]+ls2[2]+ls2[3];
    atomicAdd(stats,     (double)a);
    atomicAdd(stats + 1, (double)a2);
  }
}

// ================= kernel 2: precompute scalars / folded weights / MFMA B-frags =================
__global__ __launch_bounds__(256) void k_prep(const double* __restrict__ stats,
    const float* __restrict__ w1, const float* __restrict__ w2, const float* __restrict__ w3,
    const float* __restrict__ g1, const float* __restrict__ b1, const float* __restrict__ rm1, const float* __restrict__ rv1,
    const float* __restrict__ g2, const float* __restrict__ b2, const float* __restrict__ rm2, const float* __restrict__ rv2,
    const float* __restrict__ g3, const float* __restrict__ b3, const float* __restrict__ rm3, const float* __restrict__ rv3,
    float* __restrict__ cst, unsigned* __restrict__ wsB2, unsigned* __restrict__ wsB3){
  int t = threadIdx.x;
  if (t == 0){
    double n = (double)NPIX;
    double mean = stats[0] / n;
    double var  = (stats[1] - n * mean * mean) / (n - 1.0);
    double sd   = sqrt(var);
    cst[0] = (float)mean;
    cst[1] = (float)(1.0 / (sd + 1e-6));
  }
  if (t < 144){
    int c = t / 9, k = t % 9;
    float s = 0.f;
    for (int f = 0; f < TT; f++) s += w1[c*45 + f*9 + k];
    cst[2 + t] = s;
  }
  if (t < 16){
    float s1 = g1[t] * rsqrtf(rv1[t] + 1e-5f);
    cst[146 + t] = s1; cst[162 + t] = b1[t] - rm1[t] * s1;
    float s2 = g2[t] * rsqrtf(rv2[t] + 1e-5f);
    cst[178 + t] = s2; cst[194 + t] = b2[t] - rm2[t] * s2;
    float s3 = g3[t] * rsqrtf(rv3[t] + 1e-5f);
    cst[210 + t] = s3; cst[226 + t] = b3[t] - rm3[t] * s3;
  }
  // B-fragments for 16x16x32 bf16 MFMA, 5 tap-pair MFMAs (tap 9 = zero pad).
  // B[k][n]: n = lane&15, k = (lane>>4)*8 + j ; k -> tap = 2m + (k>>4), ci = k&15.
  // Packed as uint (2 bf16) : wsB[m*256 + lane*4 + jj] holds elements j=2jj,2jj+1.
  for (int it = 0; it < 5; it++){
    int idx = it * 256 + t;          // 0..1279
    int m = idx >> 8, rem = idx & 255;
    int L = rem >> 2, jj = rem & 3;
    int out = L & 15, q = L >> 4;
    unsigned v2 = 0, v3 = 0;
    #pragma unroll
    for (int h = 0; h < 2; h++){
      int j = 2*jj + h;
      int k = q*8 + j;
      int tap = 2*m + (k >> 4);
      int ci = k & 15;
      unsigned bv2 = 0, bv3 = 0;
      if (tap < 9){
        bv2 = f2bf(w2[out*144 + ci*9 + tap]);
        bv3 = f2bf(w3[out*144 + ci*9 + tap]);
      }
      v2 |= bv2 << (16*h);
      v3 |= bv3 << (16*h);
    }
    wsB2[idx] = v2; wsB3[idx] = v3;
  }
}

// ================= kernel 3: conv1 (1->16ch, dil 1) + BN + ReLU =================
__global__ __launch_bounds__(256) void k_conv1(const float* __restrict__ acc,
                                               const float* __restrict__ C,
                                               uint4* __restrict__ h1){
  int i = blockIdx.x * 256 + threadIdx.x;
  int b = i >> 18, p = i & (HWSZ - 1);
  int y = p >> 9, x = p & 511;
  float mean = C[0], inv = C[1];
  const float* ab = acc + ((size_t)b << 18);
  float a[MID];
  #pragma unroll
  for (int o = 0; o < MID; o++) a[o] = 0.f;
  #pragma unroll
  for (int ky = 0; ky < 3; ky++){
    int yy = y + ky - 1;
    if ((unsigned)yy >= HH) continue;
    #pragma unroll
    for (int kx = 0; kx < 3; kx++){
      int xx = x + kx - 1;
      if ((unsigned)xx >= WW) continue;
      float m = (ab[(yy << 9) + xx] - mean) * inv;
      int k = ky * 3 + kx;
      #pragma unroll
      for (int o = 0; o < MID; o++) a[o] = fmaf(C[2 + o*9 + k], m, a[o]);
    }
  }
  unsigned pk[8];
  #pragma unroll
  for (int j = 0; j < 8; j++){
    float v0 = fmaxf(0.f, fmaf(a[2*j],   C[146 + 2*j],   C[162 + 2*j]));
    float v1 = fmaxf(0.f, fmaf(a[2*j+1], C[146 + 2*j+1], C[162 + 2*j+1]));
    pk[j] = (unsigned)f2bf(v0) | ((unsigned)f2bf(v1) << 16);
  }
  uint4* dst = h1 + (size_t)i * 2;
  dst[0] = make_uint4(pk[0], pk[1], pk[2], pk[3]);
  dst[1] = make_uint4(pk[4], pk[5], pk[6], pk[7]);
}

// ---------- MFMA conv core: one 16-px group, 9 taps as 5 K=32 MFMAs ----------
// A[m=lane&15][k=(lane>>4)*8+j] : quad 0/1 -> tap 2m ch 0-7/8-15, quad 2/3 -> tap 2m+1.
template<int DIL>
__device__ inline f32x4 convMFMA(const uint4* __restrict__ hin, const uint4 bfrag[5],
                                 int b, int y, int x0, int lane){
  f32x4 acc = {0.f, 0.f, 0.f, 0.f};
  int col = lane & 15, q = lane >> 4;
  int chSel = q & 1;
  bool hiTap = (q >= 2);
  #pragma unroll
  for (int m = 0; m < 5; m++){
    const int ta = 2*m, tb = 2*m + 1;
    int dy = (hiTap ? tb/3 : ta/3) - 1;
    int dx = (hiTap ? tb%3 : ta%3) - 1;
    bool tv = hiTap ? (tb < 9) : (ta < 9);
    int yy = y + dy * DIL;
    int xx = x0 + col + dx * DIL;
    bool valid = tv && ((unsigned)yy < HH) && ((unsigned)xx < WW);
    U4B a; a.u = make_uint4(0u, 0u, 0u, 0u);
    if (valid) a.u = hin[(((unsigned)((b << 18) | (yy << 9) | xx)) << 1) | (unsigned)chSel];
    U4B bb; bb.u = bfrag[m];
    acc = __builtin_amdgcn_mfma_f32_16x16x32_bf16(a.h, bb.h, acc, 0, 0, 0);
  }
  return acc;
}

// ================= kernel 4: conv2 (16->16, dil 2) via MFMA + BN + ReLU =================
__global__ __launch_bounds__(256) void k_conv2m(const uint4* __restrict__ h1,
                                                const float* __restrict__ C,
                                                const unsigned* __restrict__ wsB2,
                                                uint4* __restrict__ h2){
  __shared__ float Lh[4][64][18];
  int lane = threadIdx.x & 63, wv = threadIdx.x >> 6;
  int w = blockIdx.x * 4 + wv;
  int base = w << 6;
  int b = base >> 18, rem = base & (HWSZ - 1);
  int y = rem >> 9, wx = rem & 511;
  uint4 bfrag[5];
  #pragma unroll
  for (int m = 0; m < 5; m++) bfrag[m] = ((const uint4*)wsB2)[m*64 + lane];
  int col = lane & 15, q = lane >> 4;
  float sc = C[178 + col], bi = C[194 + col];
  #pragma unroll
  for (int g = 0; g < 4; g++){
    f32x4 acc = convMFMA<2>(h1, bfrag, b, y, wx + g*16, lane);
    #pragma unroll
    for (int r = 0; r < 4; r++){
      int pix = g*16 + q*4 + r;
      Lh[wv][pix][col] = fmaxf(0.f, fmaf(acc[r], sc, bi));
    }
  }
  __syncthreads();
  unsigned pk[8];
  #pragma unroll
  for (int j = 0; j < 8; j++){
    float v0 = Lh[wv][lane][2*j], v1 = Lh[wv][lane][2*j + 1];
    pk[j] = (unsigned)f2bf(v0) | ((unsigned)f2bf(v1) << 16);
  }
  uint4* dst = h2 + (size_t)(base + lane) * 2;
  dst[0] = make_uint4(pk[0], pk[1], pk[2], pk[3]);
  dst[1] = make_uint4(pk[4], pk[5], pk[6], pk[7]);
}

// ======== kernel 5: conv3 (dil 4, MFMA) + BN + ReLU + 1x1 w4 + sigmoid + enhance ========
__global__ __launch_bounds__(256) void k_conv3m(const uint4* __restrict__ h2,
                                                const float* __restrict__ C,
                                                const unsigned* __restrict__ wsB3,
                                                const float* __restrict__ w4,
                                                const float* __restrict__ bias,
                                                const float* __restrict__ xal,
                                                float* __restrict__ out){
  __shared__ float Lh[4][64][18];
  int lane = threadIdx.x & 63, wv = threadIdx.x >> 6;
  int w = blockIdx.x * 4 + wv;
  int base = w << 6;
  int b = base >> 18, rem = base & (HWSZ - 1);
  int y = rem >> 9, wx = rem & 511;
  uint4 bfrag[5];
  #pragma unroll
  for (int m = 0; m < 5; m++) bfrag[m] = ((const uint4*)wsB3)[m*64 + lane];
  int col = lane & 15, q = lane >> 4;
  float sc = C[210 + col], bi = C[226 + col];
  #pragma unroll
  for (int g = 0; g < 4; g++){
    f32x4 acc = convMFMA<4>(h2, bfrag, b, y, wx + g*16, lane);
    #pragma unroll
    for (int r = 0; r < 4; r++){
      int pix = g*16 + q*4 + r;
      Lh[wv][pix][col] = fmaxf(0.f, fmaf(acc[r], sc, bi));
    }
  }
  __syncthreads();
  // lane owns pixel (wx + lane): read its 16 channels, full scalar epilogue
  float h3[MID];
  #pragma unroll
  for (int j = 0; j < MID; j++) h3[j] = Lh[wv][lane][j];
  int px = wx + lane;
  float bs = bias[0];
  #pragma unroll
  for (int t = 0; t < TT; t++){
    const float* xb = xal + ((size_t)(b*TT + t) << 18);
    float ov = 0.f;
    #pragma unroll
    for (int k = 0; k < 9; k++){
      const float* wr = w4 + (t*9 + k) * 16;
      float s = bs;
      #pragma unroll
      for (int ci = 0; ci < MID; ci++) s = fmaf(wr[ci], h3[ci], s);
      int yy = y + k/3 - 1, xx = px + k%3 - 1;
      float xv = (((unsigned)yy < HH) && ((unsigned)xx < WW)) ? xb[(yy << 9) + xx] : 0.f;
      float kern = fmaf(10.f, __frcp_rn(1.f + __expf(-s)), 0.1f);
      ov = fmaf(kern, xv, ov);
    }
    out[((size_t)(b*TT + t) << 18) + (y << 9) + px] = ov;
  }
}

extern "C" void kernel_launch(void* const* d_in, const int* in_sizes, int n_in,
                              void* d_out, int out_size, void* d_ws, size_t ws_size,
                              hipStream_t stream){
  const float* xal = (const float*)d_in[0];
  const float* rd  = (const float*)d_in[1];
  const float* w1  = (const float*)d_in[2];
  const float* g1  = (const float*)d_in[3];
  const float* b1  = (const float*)d_in[4];
  const float* rm1 = (const float*)d_in[5];
  const float* rv1 = (const float*)d_in[6];
  const float* w2  = (const float*)d_in[7];
  const float* g2  = (const float*)d_in[8];
  const float* b2  = (const float*)d_in[9];
  const float* rm2 = (const float*)d_in[10];
  const float* rv2 = (const float*)d_in[11];
  const float* w3  = (const float*)d_in[12];
  const float* g3  = (const float*)d_in[13];
  const float* b3  = (const float*)d_in[14];
  const float* rm3 = (const float*)d_in[15];
  const float* rv3 = (const float*)d_in[16];
  const float* w4  = (const float*)d_in[17];
  const float* bias= (const float*)d_in[18];
  float* out = (float*)d_out;

  char* ws = (char*)d_ws;
  double*   stats = (double*)ws;                      // 16 B
  float*    cst   = (float*)(ws + 64);                // ~1 KB used
  unsigned* wsB2  = (unsigned*)(ws + 32768);          // 5 KB
  unsigned* wsB3  = (unsigned*)(ws + 40960);          // 5 KB
  float*    acc   = (float*)(ws + 65536);             // 8 MB
  uint4*    h1    = (uint4*)(ws + 65536 + (size_t)NPIX*4);                    // 64 MB
  uint4*    h2    = (uint4*)(ws + 65536 + (size_t)NPIX*4 + (size_t)NPIX*32);  // 64 MB

  hipMemsetAsync(stats, 0, 64, stream);
  k_acc<<<NPIX/256, 256, 0, stream>>>(rd, acc, stats);
  k_prep<<<1, 256, 0, stream>>>(stats, w1, w2, w3,
                                g1, b1, rm1, rv1,
                                g2, b2, rm2, rv2,
                                g3, b3, rm3, rv3, cst, wsB2, wsB3);
  k_conv1<<<NPIX/256, 256, 0, stream>>>(acc, cst, h1);
  k_conv2m<<<NPIX/256, 256, 0, stream>>>(h1, cst, wsB2, h2);
  k_conv3m<<<NPIX/256, 256, 0, stream>>>(h2, cst, wsB3, w4, bias, xal, out);
}

// Round 3
// 345.583 us; speedup vs baseline: 1.9866x; 1.5515x over previous
//
#include <hip/hip_runtime.h>
#include <hip/hip_bf16.h>
#include <math.h>

#define HH 512
#define WW 512
#define BB 8
#define TT 5
#define MID 16
#define HWSZ (HH*WW)      /* 262144 = 2^18 */
#define NPIX (BB*HWSZ)    /* 2097152 */

typedef __attribute__((ext_vector_type(8))) short bf16x8;
typedef __attribute__((ext_vector_type(4))) float f32x4;

// ---------- bf16 helpers ----------
__device__ inline unsigned short f2bf(float f){
  unsigned u = __float_as_uint(f);
  u = u + 0x7fffu + ((u >> 16) & 1u);     // round-to-nearest-even
  return (unsigned short)(u >> 16);
}
__device__ inline float blo(unsigned u){ return __uint_as_float(u << 16); }
__device__ inline float bhi(unsigned u){ return __uint_as_float(u & 0xffff0000u); }

union U4B { uint4 u; bf16x8 h; };

// ---------- consts layout (floats, in cst) ----------
// [0] mean  [1] inv_std
// [2..145]   w1eff[16][9]  (summed over T)
// [146..161] sc1   [162..177] bi1
// [178..193] sc2   [194..209] bi2
// [210..225] sc3   [226..241] bi3

// ================= kernel 1: accumulate |raw_diff| + per-block partial stats =================
// 2048 blocks x 256 thr, 4 px/thread (float4). No global atomics (G12: 16k same-address
// f64 atomics serialized -> 201us in R2; per-block partial stores are contention-free).
__global__ __launch_bounds__(256) void k_acc(const float* __restrict__ rd,
                                             float4* __restrict__ acc,
                                             float2* __restrict__ partial){
  int t = blockIdx.x * 256 + threadIdx.x;   // 0..524287
  int i = t << 2;
  int b = i >> 18, p = i & (HWSZ - 1);
  const float* base = rd + (size_t)b * 4 * HWSZ + p;
  float4 f0 = *(const float4*)(base);
  float4 f1 = *(const float4*)(base + HWSZ);
  float4 f2 = *(const float4*)(base + 2*HWSZ);
  float4 f3 = *(const float4*)(base + 3*HWSZ);
  float4 s4;
  s4.x = fabsf(f0.x) + fabsf(f1.x) + fabsf(f2.x) + fabsf(f3.x);
  s4.y = fabsf(f0.y) + fabsf(f1.y) + fabsf(f2.y) + fabsf(f3.y);
  s4.z = fabsf(f0.z) + fabsf(f1.z) + fabsf(f2.z) + fabsf(f3.z);
  s4.w = fabsf(f0.w) + fabsf(f1.w) + fabsf(f2.w) + fabsf(f3.w);
  acc[t] = s4;
  float s  = s4.x + s4.y + s4.z + s4.w;
  float s2 = s4.x*s4.x + s4.y*s4.y + s4.z*s4.z + s4.w*s4.w;
  #pragma unroll
  for (int off = 32; off; off >>= 1){
    s  += __shfl_down(s,  off);
    s2 += __shfl_down(s2, off);
  }
  __shared__ float ls[4], ls2[4];
  int lane = threadIdx.x & 63, wid = threadIdx.x >> 6;
  if (lane == 0){ ls[wid] = s; ls2[wid] = s2; }
  __syncthreads();
  if (threadIdx.x == 0)
    partial[blockIdx.x] = make_float2(ls[0]+ls[1]+ls[2]+ls[3],
                                      ls2[0]+ls2[1]+ls2[2]+ls2[3]);
}

// ================= kernel 2: reduce partials + folded weights / MFMA B-frags =================
__global__ __launch_bounds__(256) void k_prep(const float2* __restrict__ partial,
    const float* __restrict__ w1, const float* __restrict__ w2, const float* __restrict__ w3,
    const float* __restrict__ g1, const float* __restrict__ b1, const float* __restrict__ rm1, const float* __restrict__ rv1,
    const float* __restrict__ g2, const float* __restrict__ b2, const float* __restrict__ rm2, const float* __restrict__ rv2,
    const float* __restrict__ g3, const float* __restrict__ b3, const float* __restrict__ rm3, const float* __restrict__ rv3,
    float* __restrict__ cst, unsigned* __restrict__ wsB2, unsigned* __restrict__ wsB3){
  int t = threadIdx.x;
  // ---- reduce 2048 float2 partials in f64 ----
  double s = 0.0, s2 = 0.0;
  for (int j = t; j < 2048; j += 256){
    float2 v = partial[j];
    s += (double)v.x; s2 += (double)v.y;
  }
  #pragma unroll
  for (int off = 32; off; off >>= 1){
    s  += __shfl_down(s,  off);
    s2 += __shfl_down(s2, off);
  }
  __shared__ double ds[4], ds2[4];
  int lane = t & 63, wid = t >> 6;
  if (lane == 0){ ds[wid] = s; ds2[wid] = s2; }
  __syncthreads();
  if (t == 0){
    double S  = ds[0]+ds[1]+ds[2]+ds[3];
    double S2 = ds2[0]+ds2[1]+ds2[2]+ds2[3];
    double n = (double)NPIX;
    double mean = S / n;
    double var  = (S2 - n * mean * mean) / (n - 1.0);
    double sd   = sqrt(var);
    cst[0] = (float)mean;
    cst[1] = (float)(1.0 / (sd + 1e-6));
  }
  if (t < 144){
    int c = t / 9, k = t % 9;
    float sw = 0.f;
    for (int f = 0; f < TT; f++) sw += w1[c*45 + f*9 + k];
    cst[2 + t] = sw;
  }
  if (t < 16){
    float s1 = g1[t] * rsqrtf(rv1[t] + 1e-5f);
    cst[146 + t] = s1; cst[162 + t] = b1[t] - rm1[t] * s1;
    float c2 = g2[t] * rsqrtf(rv2[t] + 1e-5f);
    cst[178 + t] = c2; cst[194 + t] = b2[t] - rm2[t] * c2;
    float c3 = g3[t] * rsqrtf(rv3[t] + 1e-5f);
    cst[210 + t] = c3; cst[226 + t] = b3[t] - rm3[t] * c3;
  }
  // B-fragments for 16x16x32 bf16 MFMA, 5 tap-pair MFMAs (tap 9 = zero pad).
  // B[k][n]: n = lane&15, k = (lane>>4)*8 + j ; k -> tap = 2m + (k>>4), ci = k&15.
  for (int it = 0; it < 5; it++){
    int idx = it * 256 + t;          // 0..1279
    int m = idx >> 8, rem = idx & 255;
    int L = rem >> 2, jj = rem & 3;
    int out = L & 15, q = L >> 4;
    unsigned v2 = 0, v3 = 0;
    #pragma unroll
    for (int h = 0; h < 2; h++){
      int j = 2*jj + h;
      int k = q*8 + j;
      int tap = 2*m + (k >> 4);
      int ci = k & 15;
      unsigned bv2 = 0, bv3 = 0;
      if (tap < 9){
        bv2 = f2bf(w2[out*144 + ci*9 + tap]);
        bv3 = f2bf(w3[out*144 + ci*9 + tap]);
      }
      v2 |= bv2 << (16*h);
      v3 |= bv3 << (16*h);
    }
    wsB2[idx] = v2; wsB3[idx] = v3;
  }
}

// ================= kernel 3: conv1 (1->16ch, dil 1) + BN + ReLU =================
__global__ __launch_bounds__(256) void k_conv1(const float* __restrict__ acc,
                                               const float* __restrict__ C,
                                               uint4* __restrict__ h1){
  int i = blockIdx.x * 256 + threadIdx.x;
  int b = i >> 18, p = i & (HWSZ - 1);
  int y = p >> 9, x = p & 511;
  float mean = C[0], inv = C[1];
  const float* ab = acc + ((size_t)b << 18);
  float a[MID];
  #pragma unroll
  for (int o = 0; o < MID; o++) a[o] = 0.f;
  #pragma unroll
  for (int ky = 0; ky < 3; ky++){
    int yy = y + ky - 1;
    if ((unsigned)yy >= HH) continue;
    #pragma unroll
    for (int kx = 0; kx < 3; kx++){
      int xx = x + kx - 1;
      if ((unsigned)xx >= WW) continue;
      float m = (ab[(yy << 9) + xx] - mean) * inv;
      int k = ky * 3 + kx;
      #pragma unroll
      for (int o = 0; o < MID; o++) a[o] = fmaf(C[2 + o*9 + k], m, a[o]);
    }
  }
  unsigned pk[8];
  #pragma unroll
  for (int j = 0; j < 8; j++){
    float v0 = fmaxf(0.f, fmaf(a[2*j],   C[146 + 2*j],   C[162 + 2*j]));
    float v1 = fmaxf(0.f, fmaf(a[2*j+1], C[146 + 2*j+1], C[162 + 2*j+1]));
    pk[j] = (unsigned)f2bf(v0) | ((unsigned)f2bf(v1) << 16);
  }
  uint4* dst = h1 + (size_t)i * 2;
  dst[0] = make_uint4(pk[0], pk[1], pk[2], pk[3]);
  dst[1] = make_uint4(pk[4], pk[5], pk[6], pk[7]);
}

// ---------- MFMA conv core: one 16-px group, 9 taps as 5 K=32 MFMAs ----------
// A[m=lane&15][k=(lane>>4)*8+j] : quad 0/1 -> tap 2m ch 0-7/8-15, quad 2/3 -> tap 2m+1.
template<int DIL>
__device__ inline f32x4 convMFMA(const uint4* __restrict__ hin, const uint4 bfrag[5],
                                 int b, int y, int x0, int lane){
  f32x4 acc = {0.f, 0.f, 0.f, 0.f};
  int col = lane & 15, q = lane >> 4;
  int chSel = q & 1;
  bool hiTap = (q >= 2);
  #pragma unroll
  for (int m = 0; m < 5; m++){
    const int ta = 2*m, tb = 2*m + 1;
    int dy = (hiTap ? tb/3 : ta/3) - 1;
    int dx = (hiTap ? tb%3 : ta%3) - 1;
    bool tv = hiTap ? (tb < 9) : (ta < 9);
    int yy = y + dy * DIL;
    int xx = x0 + col + dx * DIL;
    bool valid = tv && ((unsigned)yy < HH) && ((unsigned)xx < WW);
    U4B a; a.u = make_uint4(0u, 0u, 0u, 0u);
    if (valid) a.u = hin[(((unsigned)((b << 18) | (yy << 9) | xx)) << 1) | (unsigned)chSel];
    U4B bb; bb.u = bfrag[m];
    acc = __builtin_amdgcn_mfma_f32_16x16x32_bf16(a.h, bb.h, acc, 0, 0, 0);
  }
  return acc;
}

// ================= kernel 4: conv2 (16->16, dil 2) via MFMA + BN + ReLU =================
__global__ __launch_bounds__(256) void k_conv2m(const uint4* __restrict__ h1,
                                                const float* __restrict__ C,
                                                const unsigned* __restrict__ wsB2,
                                                uint4* __restrict__ h2){
  __shared__ float Lh[4][64][18];
  int lane = threadIdx.x & 63, wv = threadIdx.x >> 6;
  int w = blockIdx.x * 4 + wv;
  int base = w << 6;
  int b = base >> 18, rem = base & (HWSZ - 1);
  int y = rem >> 9, wx = rem & 511;
  uint4 bfrag[5];
  #pragma unroll
  for (int m = 0; m < 5; m++) bfrag[m] = ((const uint4*)wsB2)[m*64 + lane];
  int col = lane & 15, q = lane >> 4;
  float sc = C[178 + col], bi = C[194 + col];
  #pragma unroll
  for (int g = 0; g < 4; g++){
    f32x4 acc = convMFMA<2>(h1, bfrag, b, y, wx + g*16, lane);
    #pragma unroll
    for (int r = 0; r < 4; r++){
      int pix = g*16 + q*4 + r;
      Lh[wv][pix][col] = fmaxf(0.f, fmaf(acc[r], sc, bi));
    }
  }
  __syncthreads();
  unsigned pk[8];
  #pragma unroll
  for (int j = 0; j < 8; j++){
    float v0 = Lh[wv][lane][2*j], v1 = Lh[wv][lane][2*j + 1];
    pk[j] = (unsigned)f2bf(v0) | ((unsigned)f2bf(v1) << 16);
  }
  uint4* dst = h2 + (size_t)(base + lane) * 2;
  dst[0] = make_uint4(pk[0], pk[1], pk[2], pk[3]);
  dst[1] = make_uint4(pk[4], pk[5], pk[6], pk[7]);
}

// ======== kernel 5: conv3 (dil 4, MFMA) + BN + ReLU + 1x1 w4 + sigmoid + enhance ========
__global__ __launch_bounds__(256) void k_conv3m(const uint4* __restrict__ h2,
                                                const float* __restrict__ C,
                                                const unsigned* __restrict__ wsB3,
                                                const float* __restrict__ w4,
                                                const float* __restrict__ bias,
                                                const float* __restrict__ xal,
                                                float* __restrict__ out){
  __shared__ float Lh[4][64][18];
  int lane = threadIdx.x & 63, wv = threadIdx.x >> 6;
  int w = blockIdx.x * 4 + wv;
  int base = w << 6;
  int b = base >> 18, rem = base & (HWSZ - 1);
  int y = rem >> 9, wx = rem & 511;
  uint4 bfrag[5];
  #pragma unroll
  for (int m = 0; m < 5; m++) bfrag[m] = ((const uint4*)wsB3)[m*64 + lane];
  int col = lane & 15, q = lane >> 4;
  float sc = C[210 + col], bi = C[226 + col];
  #pragma unroll
  for (int g = 0; g < 4; g++){
    f32x4 acc = convMFMA<4>(h2, bfrag, b, y, wx + g*16, lane);
    #pragma unroll
    for (int r = 0; r < 4; r++){
      int pix = g*16 + q*4 + r;
      Lh[wv][pix][col] = fmaxf(0.f, fmaf(acc[r], sc, bi));
    }
  }
  __syncthreads();
  // lane owns pixel (wx + lane): read its 16 channels, full scalar epilogue
  float h3[MID];
  #pragma unroll
  for (int j = 0; j < MID; j++) h3[j] = Lh[wv][lane][j];
  int px = wx + lane;
  float bs = bias[0];
  #pragma unroll
  for (int t = 0; t < TT; t++){
    const float* xb = xal + ((size_t)(b*TT + t) << 18);
    float ov = 0.f;
    #pragma unroll
    for (int k = 0; k < 9; k++){
      const float* wr = w4 + (t*9 + k) * 16;
      float s = bs;
      #pragma unroll
      for (int ci = 0; ci < MID; ci++) s = fmaf(wr[ci], h3[ci], s);
      int yy = y + k/3 - 1, xx = px + k%3 - 1;
      float xv = (((unsigned)yy < HH) && ((unsigned)xx < WW)) ? xb[(yy << 9) + xx] : 0.f;
      float kern = fmaf(10.f, __frcp_rn(1.f + __expf(-s)), 0.1f);
      ov = fmaf(kern, xv, ov);
    }
    out[((size_t)(b*TT + t) << 18) + (y << 9) + px] = ov;
  }
}

extern "C" void kernel_launch(void* const* d_in, const int* in_sizes, int n_in,
                              void* d_out, int out_size, void* d_ws, size_t ws_size,
                              hipStream_t stream){
  const float* xal = (const float*)d_in[0];
  const float* rd  = (const float*)d_in[1];
  const float* w1  = (const float*)d_in[2];
  const float* g1  = (const float*)d_in[3];
  const float* b1  = (const float*)d_in[4];
  const float* rm1 = (const float*)d_in[5];
  const float* rv1 = (const float*)d_in[6];
  const float* w2  = (const float*)d_in[7];
  const float* g2  = (const float*)d_in[8];
  const float* b2  = (const float*)d_in[9];
  const float* rm2 = (const float*)d_in[10];
  const float* rv2 = (const float*)d_in[11];
  const float* w3  = (const float*)d_in[12];
  const float* g3  = (const float*)d_in[13];
  const float* b3  = (const float*)d_in[14];
  const float* rm3 = (const float*)d_in[15];
  const float* rv3 = (const float*)d_in[16];
  const float* w4  = (const float*)d_in[17];
  const float* bias= (const float*)d_in[18];
  float* out = (float*)d_out;

  char* ws = (char*)d_ws;
  float2*   partial = (float2*)ws;                    // 16 KB
  float*    cst   = (float*)(ws + 16384);             // ~1 KB used
  unsigned* wsB2  = (unsigned*)(ws + 32768);          // 5 KB
  unsigned* wsB3  = (unsigned*)(ws + 40960);          // 5 KB
  float*    acc   = (float*)(ws + 65536);             // 8 MB
  uint4*    h1    = (uint4*)(ws + 65536 + (size_t)NPIX*4);                    // 64 MB
  uint4*    h2    = (uint4*)(ws + 65536 + (size_t)NPIX*4 + (size_t)NPIX*32);  // 64 MB

  k_acc<<<2048, 256, 0, stream>>>(rd, (float4*)acc, partial);
  k_prep<<<1, 256, 0, stream>>>(partial, w1, w2, w3,
                                g1, b1, rm1, rv1,
                                g2, b2, rm2, rv2,
                                g3, b3, rm3, rv3, cst, wsB2, wsB3);
  k_conv1<<<NPIX/256, 256, 0, stream>>>(acc, cst, h1);
  k_conv2m<<<NPIX/256, 256, 0, stream>>>(h1, cst, wsB2, h2);
  k_conv3m<<<NPIX/256, 256, 0, stream>>>(h2, cst, wsB3, w4, bias, xal, out);
}

// Round 4
// 322.099 us; speedup vs baseline: 2.1314x; 1.0729x over previous
//
#include <hip/hip_runtime.h>
#include <hip/hip_bf16.h>
#include <math.h>

#define HH 512
#define WW 512
#define BB 8
#define TT 5
#define MID 16
#define HWSZ (HH*WW)      /* 262144 = 2^18 */
#define NPIX (BB*HWSZ)    /* 2097152 */

typedef __attribute__((ext_vector_type(8))) short bf16x8;
typedef __attribute__((ext_vector_type(4))) float f32x4;

// ---------- bf16 helpers ----------
__device__ inline unsigned short f2bf(float f){
  unsigned u = __float_as_uint(f);
  u = u + 0x7fffu + ((u >> 16) & 1u);     // round-to-nearest-even
  return (unsigned short)(u >> 16);
}
__device__ inline float blo(unsigned u){ return __uint_as_float(u << 16); }
__device__ inline float bhi(unsigned u){ return __uint_as_float(u & 0xffff0000u); }

union U4B { uint4 u; bf16x8 h; };

// ---------- consts layout (floats, in cst) ----------
// [0] mean  [1] inv_std
// [2..145]   w1eff[16][9]  (summed over T)
// [146..161] sc1   [162..177] bi1
// [178..193] sc2   [194..209] bi2
// [210..225] sc3   [226..241] bi3
// [242] bias

// ================= kernel 1: accumulate |raw_diff| + per-block partial stats =================
__global__ __launch_bounds__(256) void k_acc(const float* __restrict__ rd,
                                             float4* __restrict__ acc,
                                             float2* __restrict__ partial){
  int t = blockIdx.x * 256 + threadIdx.x;   // 0..524287
  int i = t << 2;
  int b = i >> 18, p = i & (HWSZ - 1);
  const float* base = rd + (size_t)b * 4 * HWSZ + p;
  float4 f0 = *(const float4*)(base);
  float4 f1 = *(const float4*)(base + HWSZ);
  float4 f2 = *(const float4*)(base + 2*HWSZ);
  float4 f3 = *(const float4*)(base + 3*HWSZ);
  float4 s4;
  s4.x = fabsf(f0.x) + fabsf(f1.x) + fabsf(f2.x) + fabsf(f3.x);
  s4.y = fabsf(f0.y) + fabsf(f1.y) + fabsf(f2.y) + fabsf(f3.y);
  s4.z = fabsf(f0.z) + fabsf(f1.z) + fabsf(f2.z) + fabsf(f3.z);
  s4.w = fabsf(f0.w) + fabsf(f1.w) + fabsf(f2.w) + fabsf(f3.w);
  acc[t] = s4;
  float s  = s4.x + s4.y + s4.z + s4.w;
  float s2 = s4.x*s4.x + s4.y*s4.y + s4.z*s4.z + s4.w*s4.w;
  #pragma unroll
  for (int off = 32; off; off >>= 1){
    s  += __shfl_down(s,  off);
    s2 += __shfl_down(s2, off);
  }
  __shared__ float ls[4], ls2[4];
  int lane = threadIdx.x & 63, wid = threadIdx.x >> 6;
  if (lane == 0){ ls[wid] = s; ls2[wid] = s2; }
  __syncthreads();
  if (threadIdx.x == 0)
    partial[blockIdx.x] = make_float2(ls[0]+ls[1]+ls[2]+ls[3],
                                      ls2[0]+ls2[1]+ls2[2]+ls2[3]);
}

// ================= kernel 2: reduce partials + folded weights / MFMA B-frags =================
__global__ __launch_bounds__(256) void k_prep(const float2* __restrict__ partial,
    const float* __restrict__ w1, const float* __restrict__ w2, const float* __restrict__ w3,
    const float* __restrict__ g1, const float* __restrict__ b1, const float* __restrict__ rm1, const float* __restrict__ rv1,
    const float* __restrict__ g2, const float* __restrict__ b2, const float* __restrict__ rm2, const float* __restrict__ rv2,
    const float* __restrict__ g3, const float* __restrict__ b3, const float* __restrict__ rm3, const float* __restrict__ rv3,
    const float* __restrict__ w4, const float* __restrict__ bias0,
    float* __restrict__ cst, unsigned* __restrict__ wsB2, unsigned* __restrict__ wsB3,
    uint4* __restrict__ wsB4){
  int t = threadIdx.x;
  // ---- reduce 2048 float2 partials in f64 ----
  double s = 0.0, s2 = 0.0;
  for (int j = t; j < 2048; j += 256){
    float2 v = partial[j];
    s += (double)v.x; s2 += (double)v.y;
  }
  #pragma unroll
  for (int off = 32; off; off >>= 1){
    s  += __shfl_down(s,  off);
    s2 += __shfl_down(s2, off);
  }
  __shared__ double ds[4], ds2[4];
  int lane = t & 63, wid = t >> 6;
  if (lane == 0){ ds[wid] = s; ds2[wid] = s2; }
  __syncthreads();
  if (t == 0){
    double S  = ds[0]+ds[1]+ds[2]+ds[3];
    double S2 = ds2[0]+ds2[1]+ds2[2]+ds2[3];
    double n = (double)NPIX;
    double mean = S / n;
    double var  = (S2 - n * mean * mean) / (n - 1.0);
    double sd   = sqrt(var);
    cst[0] = (float)mean;
    cst[1] = (float)(1.0 / (sd + 1e-6));
    cst[242] = bias0[0];
  }
  if (t < 144){
    int c = t / 9, k = t % 9;
    float sw = 0.f;
    for (int f = 0; f < TT; f++) sw += w1[c*45 + f*9 + k];
    cst[2 + t] = sw;
  }
  if (t < 16){
    float s1 = g1[t] * rsqrtf(rv1[t] + 1e-5f);
    cst[146 + t] = s1; cst[162 + t] = b1[t] - rm1[t] * s1;
    float c2 = g2[t] * rsqrtf(rv2[t] + 1e-5f);
    cst[178 + t] = c2; cst[194 + t] = b2[t] - rm2[t] * c2;
    float c3 = g3[t] * rsqrtf(rv3[t] + 1e-5f);
    cst[210 + t] = c3; cst[226 + t] = b3[t] - rm3[t] * c3;
  }
  // B-fragments for conv 16x16x32 bf16 MFMA, 5 tap-pair MFMAs (tap 9 = zero pad).
  for (int it = 0; it < 5; it++){
    int idx = it * 256 + t;          // 0..1279
    int m = idx >> 8, rem = idx & 255;
    int L = rem >> 2, jj = rem & 3;
    int out = L & 15, q = L >> 4;
    unsigned v2 = 0, v3 = 0;
    #pragma unroll
    for (int h = 0; h < 2; h++){
      int j = 2*jj + h;
      int k = q*8 + j;
      int tap = 2*m + (k >> 4);
      int ci = k & 15;
      unsigned bv2 = 0, bv3 = 0;
      if (tap < 9){
        bv2 = f2bf(w2[out*144 + ci*9 + tap]);
        bv3 = f2bf(w3[out*144 + ci*9 + tap]);
      }
      v2 |= bv2 << (16*h);
      v3 |= bv3 << (16*h);
    }
    wsB2[idx] = v2; wsB3[idx] = v3;
  }
  // B-fragments for w4 16x16x32 MFMA (K: ch 0..15 real, 16..31 zero).
  // 3 chunks of N=16 covering 45 outputs (+3 zero pad).
  if (t < 192){
    int c = t >> 6, L = t & 63;
    int n = L & 15, q = L >> 4;
    int o = c*16 + n;
    unsigned vv[4];
    #pragma unroll
    for (int jj = 0; jj < 4; jj++){
      unsigned pk = 0;
      #pragma unroll
      for (int h = 0; h < 2; h++){
        int j = 2*jj + h, kci = q*8 + j;
        unsigned bv = 0;
        if (kci < 16 && o < 45) bv = f2bf(w4[o*16 + kci]);
        pk |= bv << (16*h);
      }
      vv[jj] = pk;
    }
    wsB4[c*64 + L] = make_uint4(vv[0], vv[1], vv[2], vv[3]);
  }
}

// ================= kernel 3: conv1 (1->16ch, dil 1) + BN + ReLU =================
__global__ __launch_bounds__(256) void k_conv1(const float* __restrict__ acc,
                                               const float* __restrict__ C,
                                               uint4* __restrict__ h1){
  int i = blockIdx.x * 256 + threadIdx.x;
  int b = i >> 18, p = i & (HWSZ - 1);
  int y = p >> 9, x = p & 511;
  float mean = C[0], inv = C[1];
  const float* ab = acc + ((size_t)b << 18);
  float a[MID];
  #pragma unroll
  for (int o = 0; o < MID; o++) a[o] = 0.f;
  #pragma unroll
  for (int ky = 0; ky < 3; ky++){
    int yy = y + ky - 1;
    if ((unsigned)yy >= HH) continue;
    #pragma unroll
    for (int kx = 0; kx < 3; kx++){
      int xx = x + kx - 1;
      if ((unsigned)xx >= WW) continue;
      float m = (ab[(yy << 9) + xx] - mean) * inv;
      int k = ky * 3 + kx;
      #pragma unroll
      for (int o = 0; o < MID; o++) a[o] = fmaf(C[2 + o*9 + k], m, a[o]);
    }
  }
  unsigned pk[8];
  #pragma unroll
  for (int j = 0; j < 8; j++){
    float v0 = fmaxf(0.f, fmaf(a[2*j],   C[146 + 2*j],   C[162 + 2*j]));
    float v1 = fmaxf(0.f, fmaf(a[2*j+1], C[146 + 2*j+1], C[162 + 2*j+1]));
    pk[j] = (unsigned)f2bf(v0) | ((unsigned)f2bf(v1) << 16);
  }
  uint4* dst = h1 + (size_t)i * 2;
  dst[0] = make_uint4(pk[0], pk[1], pk[2], pk[3]);
  dst[1] = make_uint4(pk[4], pk[5], pk[6], pk[7]);
}

// ---------- MFMA conv core: one 16-px group, 9 taps as 5 K=32 MFMAs ----------
// A[m=lane&15][k=(lane>>4)*8+j] : quad 0/1 -> tap 2m ch 0-7/8-15, quad 2/3 -> tap 2m+1.
template<int DIL>
__device__ inline f32x4 convMFMA(const uint4* __restrict__ hin, const uint4 bfrag[5],
                                 int b, int y, int x0, int lane){
  f32x4 acc = {0.f, 0.f, 0.f, 0.f};
  int col = lane & 15, q = lane >> 4;
  int chSel = q & 1;
  bool hiTap = (q >= 2);
  #pragma unroll
  for (int m = 0; m < 5; m++){
    const int ta = 2*m, tb = 2*m + 1;
    int dy = (hiTap ? tb/3 : ta/3) - 1;
    int dx = (hiTap ? tb%3 : ta%3) - 1;
    bool tv = hiTap ? (tb < 9) : (ta < 9);
    int yy = y + dy * DIL;
    int xx = x0 + col + dx * DIL;
    bool valid = tv && ((unsigned)yy < HH) && ((unsigned)xx < WW);
    U4B a; a.u = make_uint4(0u, 0u, 0u, 0u);
    if (valid) a.u = hin[(((unsigned)((b << 18) | (yy << 9) | xx)) << 1) | (unsigned)chSel];
    U4B bb; bb.u = bfrag[m];
    acc = __builtin_amdgcn_mfma_f32_16x16x32_bf16(a.h, bb.h, acc, 0, 0, 0);
  }
  return acc;
}

// ================= kernel 4: conv2 (16->16, dil 2) via MFMA + BN + ReLU =================
__global__ __launch_bounds__(256) void k_conv2m(const uint4* __restrict__ h1,
                                                const float* __restrict__ C,
                                                const unsigned* __restrict__ wsB2,
                                                uint4* __restrict__ h2){
  __shared__ float Lh[4][64][18];
  int lane = threadIdx.x & 63, wv = threadIdx.x >> 6;
  int w = blockIdx.x * 4 + wv;
  int base = w << 6;
  int b = base >> 18, rem = base & (HWSZ - 1);
  int y = rem >> 9, wx = rem & 511;
  uint4 bfrag[5];
  #pragma unroll
  for (int m = 0; m < 5; m++) bfrag[m] = ((const uint4*)wsB2)[m*64 + lane];
  int col = lane & 15, q = lane >> 4;
  float sc = C[178 + col], bi = C[194 + col];
  #pragma unroll
  for (int g = 0; g < 4; g++){
    f32x4 acc = convMFMA<2>(h1, bfrag, b, y, wx + g*16, lane);
    #pragma unroll
    for (int r = 0; r < 4; r++){
      int pix = g*16 + q*4 + r;
      Lh[wv][pix][col] = fmaxf(0.f, fmaf(acc[r], sc, bi));
    }
  }
  __syncthreads();
  unsigned pk[8];
  #pragma unroll
  for (int j = 0; j < 8; j++){
    float v0 = Lh[wv][lane][2*j], v1 = Lh[wv][lane][2*j + 1];
    pk[j] = (unsigned)f2bf(v0) | ((unsigned)f2bf(v1) << 16);
  }
  uint4* dst = h2 + (size_t)(base + lane) * 2;
  dst[0] = make_uint4(pk[0], pk[1], pk[2], pk[3]);
  dst[1] = make_uint4(pk[4], pk[5], pk[6], pk[7]);
}

// ======== kernel 5: conv3 (dil 4, MFMA) + BN/ReLU + w4 via MFMA + sigmoid + enhance ========
// Wave-private LDS slices (no __syncthreads needed):
//   bytes [0, 3072):      h3 bf16, 64 px rows of 48 B (16 ch x 2B + 16B pad, b128-aligned)
//   bytes [3072, 10240):  kern bf16, 64 px rows of 112 B (48 vals x 2B + pad)
__global__ __launch_bounds__(256) void k_conv3m(const uint4* __restrict__ h2,
                                                const float* __restrict__ C,
                                                const unsigned* __restrict__ wsB3,
                                                const uint4* __restrict__ wsB4,
                                                const float* __restrict__ xal,
                                                float* __restrict__ out){
  __shared__ uint4 LB[4][640];               // 40 KB / block
  int lane = threadIdx.x & 63, wv = threadIdx.x >> 6;
  char* myL = (char*)LB[wv];
  unsigned short* Lh = (unsigned short*)myL;            // row stride 24 shorts
  unsigned short* Lk = (unsigned short*)(myL + 3072);   // row stride 56 shorts
  int w = blockIdx.x * 4 + wv;
  int base = w << 6;
  int b = base >> 18, rem = base & (HWSZ - 1);
  int y = rem >> 9, wx = rem & 511;
  uint4 bfrag[5];
  #pragma unroll
  for (int m = 0; m < 5; m++) bfrag[m] = ((const uint4*)wsB3)[m*64 + lane];
  uint4 bw[3];
  #pragma unroll
  for (int c = 0; c < 3; c++) bw[c] = wsB4[c*64 + lane];
  int col = lane & 15, q = lane >> 4;
  float sc = C[210 + col], bi = C[226 + col];
  float cb = C[242];                                    // bias
  // ---- stage 1: conv3 + BN + ReLU -> Lh (bf16) ----
  #pragma unroll
  for (int g = 0; g < 4; g++){
    f32x4 acc = convMFMA<4>(h2, bfrag, b, y, wx + g*16, lane);
    #pragma unroll
    for (int r = 0; r < 4; r++){
      float v = fmaxf(0.f, fmaf(acc[r], sc, bi));
      Lh[(g*16 + q*4 + r)*24 + col] = f2bf(v);
    }
  }
  // ---- stage 2: w4 1x1 conv via MFMA (K=16 padded to 32) + sigmoid -> Lk ----
  #pragma unroll
  for (int g = 0; g < 4; g++){
    U4B a; a.u = make_uint4(0u, 0u, 0u, 0u);
    if (q < 2) a.u = *(const uint4*)(myL + (g*16 + col)*48 + q*16);
    #pragma unroll
    for (int c = 0; c < 3; c++){
      f32x4 aw = {cb, cb, cb, cb};
      U4B bb; bb.u = bw[c];
      aw = __builtin_amdgcn_mfma_f32_16x16x32_bf16(a.h, bb.h, aw, 0, 0, 0);
      #pragma unroll
      for (int r = 0; r < 4; r++){
        float t2 = __expf(-aw[r]);
        float kern = fmaf(10.f, __frcp_rn(1.f + t2), 0.1f);
        Lk[(g*16 + q*4 + r)*56 + c*16 + col] = f2bf(kern);
      }
    }
  }
  // ---- stage 3: lane owns pixel `lane`; 45 kern x 45 patch FMAs ----
  unsigned kvf[24];
  {
    const uint4* kp = (const uint4*)(myL + 3072 + lane*112);
    #pragma unroll
    for (int jj = 0; jj < 6; jj++){
      uint4 u = kp[jj];
      kvf[4*jj] = u.x; kvf[4*jj+1] = u.y; kvf[4*jj+2] = u.z; kvf[4*jj+3] = u.w;
    }
  }
  int px = wx + lane;
  #pragma unroll
  for (int t = 0; t < TT; t++){
    const float* xb = xal + ((size_t)(b*TT + t) << 18);
    float ov = 0.f;
    #pragma unroll
    for (int k = 0; k < 9; k++){
      int n = t*9 + k;
      unsigned u = kvf[n >> 1];
      float kern = (n & 1) ? bhi(u) : blo(u);
      int yy = y + k/3 - 1, xx = px + k%3 - 1;
      float xv = (((unsigned)yy < HH) && ((unsigned)xx < WW)) ? xb[(yy << 9) + xx] : 0.f;
      ov = fmaf(kern, xv, ov);
    }
    out[((size_t)(b*TT + t) << 18) + (y << 9) + px] = ov;
  }
}

extern "C" void kernel_launch(void* const* d_in, const int* in_sizes, int n_in,
                              void* d_out, int out_size, void* d_ws, size_t ws_size,
                              hipStream_t stream){
  const float* xal = (const float*)d_in[0];
  const float* rd  = (const float*)d_in[1];
  const float* w1  = (const float*)d_in[2];
  const float* g1  = (const float*)d_in[3];
  const float* b1  = (const float*)d_in[4];
  const float* rm1 = (const float*)d_in[5];
  const float* rv1 = (const float*)d_in[6];
  const float* w2  = (const float*)d_in[7];
  const float* g2  = (const float*)d_in[8];
  const float* b2  = (const float*)d_in[9];
  const float* rm2 = (const float*)d_in[10];
  const float* rv2 = (const float*)d_in[11];
  const float* w3  = (const float*)d_in[12];
  const float* g3  = (const float*)d_in[13];
  const float* b3  = (const float*)d_in[14];
  const float* rm3 = (const float*)d_in[15];
  const float* rv3 = (const float*)d_in[16];
  const float* w4  = (const float*)d_in[17];
  const float* bias= (const float*)d_in[18];
  float* out = (float*)d_out;

  char* ws = (char*)d_ws;
  float2*   partial = (float2*)ws;                    // 16 KB
  float*    cst   = (float*)(ws + 16384);             // ~1 KB used
  unsigned* wsB2  = (unsigned*)(ws + 32768);          // 5 KB
  unsigned* wsB3  = (unsigned*)(ws + 40960);          // 5 KB
  uint4*    wsB4  = (uint4*)(ws + 49152);             // 3 KB
  float*    acc   = (float*)(ws + 65536);             // 8 MB
  uint4*    h1    = (uint4*)(ws + 65536 + (size_t)NPIX*4);                    // 64 MB
  uint4*    h2    = (uint4*)(ws + 65536 + (size_t)NPIX*4 + (size_t)NPIX*32);  // 64 MB

  k_acc<<<2048, 256, 0, stream>>>(rd, (float4*)acc, partial);
  k_prep<<<1, 256, 0, stream>>>(partial, w1, w2, w3,
                                g1, b1, rm1, rv1,
                                g2, b2, rm2, rv2,
                                g3, b3, rm3, rv3, w4, bias, cst, wsB2, wsB3, wsB4);
  k_conv1<<<NPIX/256, 256, 0, stream>>>(acc, cst, h1);
  k_conv2m<<<NPIX/256, 256, 0, stream>>>(h1, cst, wsB2, h2);
  k_conv3m<<<NPIX/256, 256, 0, stream>>>(h2, cst, wsB3, wsB4, xal, out);
}

// Round 6
// 293.909 us; speedup vs baseline: 2.3358x; 1.0959x over previous
//
#include <hip/hip_runtime.h>
#include <hip/hip_bf16.h>
#include <math.h>

#define HH 512
#define WW 512
#define BB 8
#define TT 5
#define MID 16
#define HWSZ (HH*WW)      /* 262144 = 2^18 */
#define NPIX (BB*HWSZ)    /* 2097152 */

typedef __attribute__((ext_vector_type(8))) short bf16x8;
typedef __attribute__((ext_vector_type(4))) float f32x4;

// ---------- bf16 helpers ----------
__device__ inline unsigned short f2bf(float f){          // RNE (used in prep only)
  unsigned u = __float_as_uint(f);
  u = u + 0x7fffu + ((u >> 16) & 1u);
  return (unsigned short)(u >> 16);
}
// fast round-half-up pack of two floats -> bf16 pair (2 add + 1 v_perm)
__device__ inline unsigned packpair(float a, float b){
  unsigned ua = __float_as_uint(a) + 0x8000u;
  unsigned ub = __float_as_uint(b) + 0x8000u;
  return __builtin_amdgcn_perm(ub, ua, 0x07060302u);
}
__device__ inline float blo(unsigned u){ return __uint_as_float(u << 16); }
__device__ inline float bhi(unsigned u){ return __uint_as_float(u & 0xffff0000u); }

union U4B { uint4 u; bf16x8 h; };

// ---------- consts layout (floats, in cst) ----------
// [0] mean  [1] inv_std
// [2..145]   w1eff[16][9]  (summed over T)           (conv1 scalar)
// [146..161] sc1   [162..177] bi1                    (conv1 scalar)
// [242] bias
// aligned (16B) BN copies for MFMA epilogues:
// [288..303] sc2a  [304..319] bi2a
// [320..335] sc3a  [336..351] bi3a

// ================= kernel 1: accumulate |raw_diff| + per-block partial stats =================
__global__ __launch_bounds__(256) void k_acc(const float* __restrict__ rd,
                                             float4* __restrict__ acc,
                                             float2* __restrict__ partial){
  int t = blockIdx.x * 256 + threadIdx.x;   // 0..524287
  int i = t << 2;
  int b = i >> 18, p = i & (HWSZ - 1);
  const float* base = rd + (size_t)b * 4 * HWSZ + p;
  float4 f0 = *(const float4*)(base);
  float4 f1 = *(const float4*)(base + HWSZ);
  float4 f2 = *(const float4*)(base + 2*HWSZ);
  float4 f3 = *(const float4*)(base + 3*HWSZ);
  float4 s4;
  s4.x = fabsf(f0.x) + fabsf(f1.x) + fabsf(f2.x) + fabsf(f3.x);
  s4.y = fabsf(f0.y) + fabsf(f1.y) + fabsf(f2.y) + fabsf(f3.y);
  s4.z = fabsf(f0.z) + fabsf(f1.z) + fabsf(f2.z) + fabsf(f3.z);
  s4.w = fabsf(f0.w) + fabsf(f1.w) + fabsf(f2.w) + fabsf(f3.w);
  acc[t] = s4;
  float s  = s4.x + s4.y + s4.z + s4.w;
  float s2 = s4.x*s4.x + s4.y*s4.y + s4.z*s4.z + s4.w*s4.w;
  #pragma unroll
  for (int off = 32; off; off >>= 1){
    s  += __shfl_down(s,  off);
    s2 += __shfl_down(s2, off);
  }
  __shared__ float ls[4], ls2[4];
  int lane = threadIdx.x & 63, wid = threadIdx.x >> 6;
  if (lane == 0){ ls[wid] = s; ls2[wid] = s2; }
  __syncthreads();
  if (threadIdx.x == 0)
    partial[blockIdx.x] = make_float2(ls[0]+ls[1]+ls[2]+ls[3],
                                      ls2[0]+ls2[1]+ls2[2]+ls2[3]);
}

// ================= kernel 2: reduce partials + folded weights / MFMA frags =================
__global__ __launch_bounds__(256) void k_prep(const float2* __restrict__ partial,
    const float* __restrict__ w1, const float* __restrict__ w2, const float* __restrict__ w3,
    const float* __restrict__ g1, const float* __restrict__ b1, const float* __restrict__ rm1, const float* __restrict__ rv1,
    const float* __restrict__ g2, const float* __restrict__ b2, const float* __restrict__ rm2, const float* __restrict__ rv2,
    const float* __restrict__ g3, const float* __restrict__ b3, const float* __restrict__ rm3, const float* __restrict__ rv3,
    const float* __restrict__ w4, const float* __restrict__ bias0,
    float* __restrict__ cst, unsigned* __restrict__ wsB2, unsigned* __restrict__ wsB3,
    uint4* __restrict__ wsB4){
  int t = threadIdx.x;
  // ---- reduce 2048 float2 partials in f64 ----
  double s = 0.0, s2 = 0.0;
  for (int j = t; j < 2048; j += 256){
    float2 v = partial[j];
    s += (double)v.x; s2 += (double)v.y;
  }
  #pragma unroll
  for (int off = 32; off; off >>= 1){
    s  += __shfl_down(s,  off);
    s2 += __shfl_down(s2, off);
  }
  __shared__ double ds[4], ds2[4];
  int lane = t & 63, wid = t >> 6;
  if (lane == 0){ ds[wid] = s; ds2[wid] = s2; }
  __syncthreads();
  if (t == 0){
    double S  = ds[0]+ds[1]+ds[2]+ds[3];
    double S2 = ds2[0]+ds2[1]+ds2[2]+ds2[3];
    double n = (double)NPIX;
    double mean = S / n;
    double var  = (S2 - n * mean * mean) / (n - 1.0);
    double sd   = sqrt(var);
    cst[0] = (float)mean;
    cst[1] = (float)(1.0 / (sd + 1e-6));
    cst[242] = bias0[0];
  }
  if (t < 144){
    int c = t / 9, k = t % 9;
    float sw = 0.f;
    for (int f = 0; f < TT; f++) sw += w1[c*45 + f*9 + k];
    cst[2 + t] = sw;
  }
  if (t < 16){
    float s1 = g1[t] * rsqrtf(rv1[t] + 1e-5f);
    cst[146 + t] = s1; cst[162 + t] = b1[t] - rm1[t] * s1;
    float c2 = g2[t] * rsqrtf(rv2[t] + 1e-5f);
    cst[288 + t] = c2; cst[304 + t] = b2[t] - rm2[t] * c2;
    float c3 = g3[t] * rsqrtf(rv3[t] + 1e-5f);
    cst[320 + t] = c3; cst[336 + t] = b3[t] - rm3[t] * c3;
  }
  // Weight fragments for conv 16x16x32 bf16 MFMA (used as A operand; layout is
  // index-symmetric with B): lane holds [out=lane&15][k=(lane>>4)*8+j],
  // k -> tap = 2m + (k>>4), ci = k&15; tap 9 zero-padded.
  for (int it = 0; it < 5; it++){
    int idx = it * 256 + t;          // 0..1279
    int m = idx >> 8, rem = idx & 255;
    int L = rem >> 2, jj = rem & 3;
    int out = L & 15, q = L >> 4;
    unsigned v2 = 0, v3 = 0;
    #pragma unroll
    for (int h = 0; h < 2; h++){
      int j = 2*jj + h;
      int k = q*8 + j;
      int tap = 2*m + (k >> 4);
      int ci = k & 15;
      unsigned bv2 = 0, bv3 = 0;
      if (tap < 9){
        bv2 = f2bf(w2[out*144 + ci*9 + tap]);
        bv3 = f2bf(w3[out*144 + ci*9 + tap]);
      }
      v2 |= bv2 << (16*h);
      v3 |= bv3 << (16*h);
    }
    wsB2[idx] = v2; wsB3[idx] = v3;
  }
  // B-fragments for w4 16x16x32 MFMA (K: ch 0..15 real, 16..31 zero), 3 N-chunks.
  if (t < 192){
    int c = t >> 6, L = t & 63;
    int n = L & 15, q = L >> 4;
    int o = c*16 + n;
    unsigned vv[4];
    #pragma unroll
    for (int jj = 0; jj < 4; jj++){
      unsigned pk = 0;
      #pragma unroll
      for (int h = 0; h < 2; h++){
        int j = 2*jj + h, kci = q*8 + j;
        unsigned bv = 0;
        if (kci < 16 && o < 45) bv = f2bf(w4[o*16 + kci]);
        pk |= bv << (16*h);
      }
      vv[jj] = pk;
    }
    wsB4[c*64 + L] = make_uint4(vv[0], vv[1], vv[2], vv[3]);
  }
}

// ================= kernel 3: conv1 (1->16ch, dil 1) + BN + ReLU (scalar) =================
__global__ __launch_bounds__(256) void k_conv1(const float* __restrict__ acc,
                                               const float* __restrict__ C,
                                               uint4* __restrict__ h1){
  int i = blockIdx.x * 256 + threadIdx.x;
  int b = i >> 18, p = i & (HWSZ - 1);
  int y = p >> 9, x = p & 511;
  float mean = C[0], inv = C[1];
  const float* ab = acc + ((size_t)b << 18);
  float a[MID];
  #pragma unroll
  for (int o = 0; o < MID; o++) a[o] = 0.f;
  #pragma unroll
  for (int ky = 0; ky < 3; ky++){
    int yy = y + ky - 1;
    if ((unsigned)yy >= HH) continue;
    #pragma unroll
    for (int kx = 0; kx < 3; kx++){
      int xx = x + kx - 1;
      if ((unsigned)xx >= WW) continue;
      float m = (ab[(yy << 9) + xx] - mean) * inv;
      int k = ky * 3 + kx;
      #pragma unroll
      for (int o = 0; o < MID; o++) a[o] = fmaf(C[2 + o*9 + k], m, a[o]);
    }
  }
  unsigned pk[8];
  #pragma unroll
  for (int j = 0; j < 8; j++){
    float v0 = fmaxf(0.f, fmaf(a[2*j],   C[146 + 2*j],   C[162 + 2*j]));
    float v1 = fmaxf(0.f, fmaf(a[2*j+1], C[146 + 2*j+1], C[162 + 2*j+1]));
    pk[j] = (unsigned)f2bf(v0) | ((unsigned)f2bf(v1) << 16);
  }
  uint4* dst = h1 + (size_t)i * 2;
  dst[0] = make_uint4(pk[0], pk[1], pk[2], pk[3]);
  dst[1] = make_uint4(pk[4], pk[5], pk[6], pk[7]);
}

// ---------- swapped MFMA conv core: A = weights, B = pixel patches ----------
// C layout: col = lane&15 = pixel (x0+col), row = (lane>>4)*4+r = out-channel.
template<int DIL>
__device__ inline f32x4 convW(const uint4* __restrict__ hin, const uint4 wfrag[5],
                              int b, int y, int x0, int col, int q, f32x4 cc){
  int chSel = q & 1;
  bool hiTap = (q >= 2);
  #pragma unroll
  for (int m = 0; m < 5; m++){
    const int ta = 2*m, tb = 2*m + 1;
    int dy = (hiTap ? tb/3 : ta/3) - 1;
    int dx = (hiTap ? tb%3 : ta%3) - 1;
    bool tv = hiTap ? (tb < 9) : true;
    int yy = y + dy * DIL;
    int xx = x0 + col + dx * DIL;
    bool valid = tv && ((unsigned)yy < HH) && ((unsigned)xx < WW);
    U4B a; a.u = make_uint4(0u, 0u, 0u, 0u);
    if (valid) a.u = hin[(((unsigned)((b << 18) | (yy << 9) | xx)) << 1) | (unsigned)chSel];
    U4B bb; bb.u = wfrag[m];
    cc = __builtin_amdgcn_mfma_f32_16x16x32_bf16(bb.h, a.h, cc, 0, 0, 0);
  }
  return cc;
}

// ================= kernel 4: conv2 (16->16, dil 2) MFMA, no LDS =================
__global__ __launch_bounds__(256) void k_conv2m(const uint4* __restrict__ h1,
                                                const float* __restrict__ C,
                                                const unsigned* __restrict__ wsB2,
                                                uint2* __restrict__ h2){
  int lane = threadIdx.x & 63, wv = threadIdx.x >> 6;
  int w = blockIdx.x * 4 + wv;
  int base = w << 6;
  int b = base >> 18, rem = base & (HWSZ - 1);
  int y = rem >> 9, wx = rem & 511;
  uint4 wfrag[5];
  #pragma unroll
  for (int m = 0; m < 5; m++) wfrag[m] = ((const uint4*)wsB2)[m*64 + lane];
  int col = lane & 15, q = lane >> 4;
  float4 sc = *(const float4*)&C[288 + q*4];
  float4 bi = *(const float4*)&C[304 + q*4];
  #pragma unroll
  for (int g = 0; g < 4; g++){
    f32x4 cc = {0.f, 0.f, 0.f, 0.f};
    cc = convW<2>(h1, wfrag, b, y, wx + g*16, col, q, cc);
    float v0 = fmaxf(0.f, fmaf(cc[0], sc.x, bi.x));
    float v1 = fmaxf(0.f, fmaf(cc[1], sc.y, bi.y));
    float v2 = fmaxf(0.f, fmaf(cc[2], sc.z, bi.z));
    float v3 = fmaxf(0.f, fmaf(cc[3], sc.w, bi.w));
    // NHWC16 store: pixel P, channels q*4..q*4+3 -> byte P*32 + q*8
    h2[(size_t)(base + g*16 + col)*4 + q] = make_uint2(packpair(v0, v1), packpair(v2, v3));
  }
}

// ======== kernel 5: conv3 (dil 4, MFMA) + BN/ReLU + w4 MFMA + sigmoid + enhance ========
// Per-wave LDS slice (10240 B): [0,3072) h3 bf16 rows px*48B; [3072,10240) kern bf16 rows px*112B.
__global__ __launch_bounds__(256) void k_conv3m(const uint4* __restrict__ h2,
                                                const float* __restrict__ C,
                                                const unsigned* __restrict__ wsB3,
                                                const uint4* __restrict__ wsB4,
                                                const float* __restrict__ xal,
                                                float* __restrict__ out){
  __shared__ uint4 LB[4][640];               // 40 KB / block
  int lane = threadIdx.x & 63, wv = threadIdx.x >> 6;
  char* myL = (char*)LB[wv];
  unsigned short* Lk = (unsigned short*)(myL + 3072);   // kern rows, 56 shorts stride
  int w = blockIdx.x * 4 + wv;
  int base = w << 6;
  int b = base >> 18, rem = base & (HWSZ - 1);
  int y = rem >> 9, wx = rem & 511;
  uint4 wfrag[5];
  #pragma unroll
  for (int m = 0; m < 5; m++) wfrag[m] = ((const uint4*)wsB3)[m*64 + lane];
  uint4 bw[3];
  #pragma unroll
  for (int c = 0; c < 3; c++) bw[c] = wsB4[c*64 + lane];
  int col = lane & 15, q = lane >> 4;
  float4 sc = *(const float4*)&C[320 + q*4];
  float4 bi = *(const float4*)&C[336 + q*4];
  float cb = C[242];                                    // bias

  #pragma unroll
  for (int g = 0; g < 4; g++){
    // ---- stage 1: conv3 (C: col=px, row=ch) + BN + ReLU -> h3 LDS bf16 ----
    f32x4 cc = {0.f, 0.f, 0.f, 0.f};
    cc = convW<4>(h2, wfrag, b, y, wx + g*16, col, q, cc);
    float v0 = fmaxf(0.f, fmaf(cc[0], sc.x, bi.x));
    float v1 = fmaxf(0.f, fmaf(cc[1], sc.y, bi.y));
    float v2 = fmaxf(0.f, fmaf(cc[2], sc.z, bi.z));
    float v3 = fmaxf(0.f, fmaf(cc[3], sc.w, bi.w));
    // pixel row (g*16+col), channel bytes q*8..q*8+7: one b64 write
    *(uint2*)(myL + (g*16 + col)*48 + q*8) = make_uint2(packpair(v0, v1), packpair(v2, v3));

    // ---- stage 2: w4 MFMA (A = h3 px rows, B = wsB4) + sigmoid -> kern LDS ----
    U4B a; a.u = make_uint4(0u, 0u, 0u, 0u);
    if (q < 2) a.u = *(const uint4*)(myL + (g*16 + col)*48 + q*16);
    #pragma unroll
    for (int c = 0; c < 3; c++){
      f32x4 aw = {cb, cb, cb, cb};
      U4B bb; bb.u = bw[c];
      aw = __builtin_amdgcn_mfma_f32_16x16x32_bf16(a.h, bb.h, aw, 0, 0, 0);
      #pragma unroll
      for (int r = 0; r < 4; r++){
        float e  = __expf(-aw[r]);
        float rc = __builtin_amdgcn_rcpf(1.f + e);
        float kern = fmaf(10.f, rc, 0.1f);
        unsigned u = __float_as_uint(kern) + 0x8000u;
        Lk[(g*16 + q*4 + r)*56 + c*16 + col] = (unsigned short)(u >> 16);
      }
    }
  }

  // ---- stage 3: lane owns pixel (wx+lane); 45 kern x patch FMAs ----
  unsigned kvf[24];
  {
    const uint4* kp = (const uint4*)(myL + 3072 + lane*112);
    #pragma unroll
    for (int jj = 0; jj < 6; jj++){
      uint4 u = kp[jj];
      kvf[4*jj] = u.x; kvf[4*jj+1] = u.y; kvf[4*jj+2] = u.z; kvf[4*jj+3] = u.w;
    }
  }
  int px = wx + lane;
  bool mxl = (px > 0), mxr = (px < 511), mym = (y > 0), myp = (y < 511);
  bool msk[9] = { mym&&mxl, mym, mym&&mxr,
                  mxl,      true, mxr,
                  myp&&mxl, myp, myp&&mxr };
  // row/col clamped offsets keep EVERY address in-bounds (both sides);
  // invalid taps are zeroed on the kern side.
  int rowm = mym ? -2048 : 0;
  int rowp = myp ?  2048 : 0;
  int loff = mxl ? -4 : 0;
  int roff = mxr ?  4 : 0;
  const char* base0 = (const char*)(xal + ((size_t)(b*TT) << 18) + (y << 9) + px);
  #pragma unroll
  for (int t = 0; t < TT; t++){
    const char* pc = base0 + (size_t)t * (HWSZ*4);
    const char* pm = pc + rowm;
    const char* pp = pc + rowp;
    float xv[9];
    xv[0] = *(const float*)(pm + loff);
    xv[1] = *(const float*)(pm);
    xv[2] = *(const float*)(pm + roff);
    xv[3] = *(const float*)(pc + loff);
    xv[4] = *(const float*)(pc);
    xv[5] = *(const float*)(pc + roff);
    xv[6] = *(const float*)(pp + loff);
    xv[7] = *(const float*)(pp);
    xv[8] = *(const float*)(pp + roff);
    float ov = 0.f;
    #pragma unroll
    for (int k = 0; k < 9; k++){
      int n = t*9 + k;
      unsigned u = kvf[n >> 1];
      float kf = (n & 1) ? bhi(u) : blo(u);
      float kern = msk[k] ? kf : 0.f;
      ov = fmaf(kern, xv[k], ov);
    }
    out[((size_t)(b*TT + t) << 18) + (y << 9) + px] = ov;
  }
}

extern "C" void kernel_launch(void* const* d_in, const int* in_sizes, int n_in,
                              void* d_out, int out_size, void* d_ws, size_t ws_size,
                              hipStream_t stream){
  const float* xal = (const float*)d_in[0];
  const float* rd  = (const float*)d_in[1];
  const float* w1  = (const float*)d_in[2];
  const float* g1  = (const float*)d_in[3];
  const float* b1  = (const float*)d_in[4];
  const float* rm1 = (const float*)d_in[5];
  const float* rv1 = (const float*)d_in[6];
  const float* w2  = (const float*)d_in[7];
  const float* g2  = (const float*)d_in[8];
  const float* b2  = (const float*)d_in[9];
  const float* rm2 = (const float*)d_in[10];
  const float* rv2 = (const float*)d_in[11];
  const float* w3  = (const float*)d_in[12];
  const float* g3  = (const float*)d_in[13];
  const float* b3  = (const float*)d_in[14];
  const float* rm3 = (const float*)d_in[15];
  const float* rv3 = (const float*)d_in[16];
  const float* w4  = (const float*)d_in[17];
  const float* bias= (const float*)d_in[18];
  float* out = (float*)d_out;

  char* ws = (char*)d_ws;
  float2*   partial = (float2*)ws;                    // 16 KB
  float*    cst   = (float*)(ws + 16384);             // 352 floats used
  unsigned* wsB2  = (unsigned*)(ws + 32768);          // 5 KB
  unsigned* wsB3  = (unsigned*)(ws + 40960);          // 5 KB
  uint4*    wsB4  = (uint4*)(ws + 49152);             // 3 KB
  float*    acc   = (float*)(ws + 65536);             // 8 MB
  uint4*    h1    = (uint4*)(ws + 65536 + (size_t)NPIX*4);                    // 64 MB
  char*     h2    = (char*)(ws + 65536 + (size_t)NPIX*4 + (size_t)NPIX*32);   // 64 MB

  k_acc<<<2048, 256, 0, stream>>>(rd, (float4*)acc, partial);
  k_prep<<<1, 256, 0, stream>>>(partial, w1, w2, w3,
                                g1, b1, rm1, rv1,
                                g2, b2, rm2, rv2,
                                g3, b3, rm3, rv3, w4, bias, cst, wsB2, wsB3, wsB4);
  k_conv1<<<NPIX/256, 256, 0, stream>>>(acc, cst, h1);
  k_conv2m<<<NPIX/256, 256, 0, stream>>>(h1, cst, wsB2, (uint2*)h2);
  k_conv3m<<<NPIX/256, 256, 0, stream>>>((const uint4*)h2, cst, wsB3, wsB4, xal, out);
}

// Round 7
// 272.415 us; speedup vs baseline: 2.5202x; 1.0789x over previous
//
#include <hip/hip_runtime.h>
#include <hip/hip_bf16.h>
#include <math.h>

#define HH 512
#define WW 512
#define BB 8
#define TT 5
#define MID 16
#define HWSZ (HH*WW)      /* 262144 = 2^18 */
#define NPIX (BB*HWSZ)    /* 2097152 */

typedef __attribute__((ext_vector_type(8))) short bf16x8;
typedef __attribute__((ext_vector_type(4))) float f32x4;

// ---------- bf16 helpers ----------
__device__ inline unsigned short f2bf(float f){          // RNE (used in prep only)
  unsigned u = __float_as_uint(f);
  u = u + 0x7fffu + ((u >> 16) & 1u);
  return (unsigned short)(u >> 16);
}
// fast round-half-up pack of two floats -> bf16 pair (2 add + 1 v_perm)
__device__ inline unsigned packpair(float a, float b){
  unsigned ua = __float_as_uint(a) + 0x8000u;
  unsigned ub = __float_as_uint(b) + 0x8000u;
  return __builtin_amdgcn_perm(ub, ua, 0x07060302u);
}
__device__ inline float blo(unsigned u){ return __uint_as_float(u << 16); }
__device__ inline float bhi(unsigned u){ return __uint_as_float(u & 0xffff0000u); }

union U4B { uint4 u; bf16x8 h; };

// ---------- consts layout (floats, in cst) ----------
// [0] mean  [1] inv_std
// [2..145]   w1eff[16][9]  (summed over T)
// [146..161] sc1   [162..177] bi1
// [242] bias
// aligned (16B) BN copies for MFMA epilogues:
// [288..303] sc2a  [304..319] bi2a
// [320..335] sc3a  [336..351] bi3a

// ================= kernel 1: accumulate |raw_diff| + per-block partial stats =================
__global__ __launch_bounds__(256) void k_acc(const float* __restrict__ rd,
                                             float4* __restrict__ acc,
                                             float2* __restrict__ partial){
  int t = blockIdx.x * 256 + threadIdx.x;   // 0..524287
  int i = t << 2;
  int b = i >> 18, p = i & (HWSZ - 1);
  const float* base = rd + (size_t)b * 4 * HWSZ + p;
  float4 f0 = *(const float4*)(base);
  float4 f1 = *(const float4*)(base + HWSZ);
  float4 f2 = *(const float4*)(base + 2*HWSZ);
  float4 f3 = *(const float4*)(base + 3*HWSZ);
  float4 s4;
  s4.x = fabsf(f0.x) + fabsf(f1.x) + fabsf(f2.x) + fabsf(f3.x);
  s4.y = fabsf(f0.y) + fabsf(f1.y) + fabsf(f2.y) + fabsf(f3.y);
  s4.z = fabsf(f0.z) + fabsf(f1.z) + fabsf(f2.z) + fabsf(f3.z);
  s4.w = fabsf(f0.w) + fabsf(f1.w) + fabsf(f2.w) + fabsf(f3.w);
  acc[t] = s4;
  float s  = s4.x + s4.y + s4.z + s4.w;
  float s2 = s4.x*s4.x + s4.y*s4.y + s4.z*s4.z + s4.w*s4.w;
  #pragma unroll
  for (int off = 32; off; off >>= 1){
    s  += __shfl_down(s,  off);
    s2 += __shfl_down(s2, off);
  }
  __shared__ float ls[4], ls2[4];
  int lane = threadIdx.x & 63, wid = threadIdx.x >> 6;
  if (lane == 0){ ls[wid] = s; ls2[wid] = s2; }
  __syncthreads();
  if (threadIdx.x == 0)
    partial[blockIdx.x] = make_float2(ls[0]+ls[1]+ls[2]+ls[3],
                                      ls2[0]+ls2[1]+ls2[2]+ls2[3]);
}

// ================= kernel 2: reduce partials + folded weights / MFMA frags =================
__global__ __launch_bounds__(256) void k_prep(const float2* __restrict__ partial,
    const float* __restrict__ w1, const float* __restrict__ w2, const float* __restrict__ w3,
    const float* __restrict__ g1, const float* __restrict__ b1, const float* __restrict__ rm1, const float* __restrict__ rv1,
    const float* __restrict__ g2, const float* __restrict__ b2, const float* __restrict__ rm2, const float* __restrict__ rv2,
    const float* __restrict__ g3, const float* __restrict__ b3, const float* __restrict__ rm3, const float* __restrict__ rv3,
    const float* __restrict__ w4, const float* __restrict__ bias0,
    float* __restrict__ cst, unsigned* __restrict__ wsB2, unsigned* __restrict__ wsB3,
    uint4* __restrict__ wsB4){
  int t = threadIdx.x;
  double s = 0.0, s2 = 0.0;
  for (int j = t; j < 2048; j += 256){
    float2 v = partial[j];
    s += (double)v.x; s2 += (double)v.y;
  }
  #pragma unroll
  for (int off = 32; off; off >>= 1){
    s  += __shfl_down(s,  off);
    s2 += __shfl_down(s2, off);
  }
  __shared__ double ds[4], ds2[4];
  int lane = t & 63, wid = t >> 6;
  if (lane == 0){ ds[wid] = s; ds2[wid] = s2; }
  __syncthreads();
  if (t == 0){
    double S  = ds[0]+ds[1]+ds[2]+ds[3];
    double S2 = ds2[0]+ds2[1]+ds2[2]+ds2[3];
    double n = (double)NPIX;
    double mean = S / n;
    double var  = (S2 - n * mean * mean) / (n - 1.0);
    double sd   = sqrt(var);
    cst[0] = (float)mean;
    cst[1] = (float)(1.0 / (sd + 1e-6));
    cst[242] = bias0[0];
  }
  if (t < 144){
    int c = t / 9, k = t % 9;
    float sw = 0.f;
    for (int f = 0; f < TT; f++) sw += w1[c*45 + f*9 + k];
    cst[2 + t] = sw;
  }
  if (t < 16){
    float s1 = g1[t] * rsqrtf(rv1[t] + 1e-5f);
    cst[146 + t] = s1; cst[162 + t] = b1[t] - rm1[t] * s1;
    float c2 = g2[t] * rsqrtf(rv2[t] + 1e-5f);
    cst[288 + t] = c2; cst[304 + t] = b2[t] - rm2[t] * c2;
    float c3 = g3[t] * rsqrtf(rv3[t] + 1e-5f);
    cst[320 + t] = c3; cst[336 + t] = b3[t] - rm3[t] * c3;
  }
  // Weight fragments for conv 16x16x32 bf16 MFMA (A operand; lane holds
  // [out=lane&15][k=(lane>>4)*8+j], k -> tap = 2m + (k>>4), ci = k&15; tap 9 zero).
  for (int it = 0; it < 5; it++){
    int idx = it * 256 + t;          // 0..1279
    int m = idx >> 8, rem = idx & 255;
    int L = rem >> 2, jj = rem & 3;
    int out = L & 15, q = L >> 4;
    unsigned v2 = 0, v3 = 0;
    #pragma unroll
    for (int h = 0; h < 2; h++){
      int j = 2*jj + h;
      int k = q*8 + j;
      int tap = 2*m + (k >> 4);
      int ci = k & 15;
      unsigned bv2 = 0, bv3 = 0;
      if (tap < 9){
        bv2 = f2bf(w2[out*144 + ci*9 + tap]);
        bv3 = f2bf(w3[out*144 + ci*9 + tap]);
      }
      v2 |= bv2 << (16*h);
      v3 |= bv3 << (16*h);
    }
    wsB2[idx] = v2; wsB3[idx] = v3;
  }
  // B-fragments for w4 16x16x32 MFMA (K: ch 0..15 real, 16..31 zero), 3 N-chunks.
  if (t < 192){
    int c = t >> 6, L = t & 63;
    int n = L & 15, q = L >> 4;
    int o = c*16 + n;
    unsigned vv[4];
    #pragma unroll
    for (int jj = 0; jj < 4; jj++){
      unsigned pk = 0;
      #pragma unroll
      for (int h = 0; h < 2; h++){
        int j = 2*jj + h, kci = q*8 + j;
        unsigned bv = 0;
        if (kci < 16 && o < 45) bv = f2bf(w4[o*16 + kci]);
        pk |= bv << (16*h);
      }
      vv[jj] = pk;
    }
    wsB4[c*64 + L] = make_uint4(vv[0], vv[1], vv[2], vv[3]);
  }
}

// ======== kernel 3: FUSED conv1 (scalar, LDS tile) + conv2 (MFMA from LDS) ========
// Block covers 64x8 output px. h1 tile: 68 cols x 12 rows (halo +-2 for dil-2),
// bf16 NHWC16 split into two 16B channel-planes (4-bank px stride -> 2-way = free).
#define TR 12
#define TC 68
__global__ __launch_bounds__(256) void k_conv12(const float* __restrict__ acc,
                                                const float* __restrict__ C,
                                                const unsigned* __restrict__ wsB2,
                                                uint2* __restrict__ h2){
  __shared__ uint4 PL[2][TR*TC];          // 2 x 13056 B = 25.5 KB
  int tid = threadIdx.x;
  int blk = blockIdx.x;                    // 8 xt | 64 yt | 8 b
  int xt = blk & 7, yt = (blk >> 3) & 63, b = blk >> 9;
  int y0 = yt << 3, x0 = xt << 6;
  float mean = C[0], inv = C[1];
  const float* ab = acc + ((size_t)b << 18);
  // ---- phase 1: conv1 + BN + ReLU into LDS tile; halo outside image = 0 ----
  #pragma unroll
  for (int it = 0; it < 4; it++){
    int i = it*256 + tid;
    if (i < TR*TC){
      int r = (i * 241) >> 14;             // i/68, exact for i<816
      int p = i - r*TC;
      int gy = y0 - 2 + r, gx = x0 - 2 + p;
      uint4 lo = make_uint4(0u,0u,0u,0u), hi = lo;
      if ((unsigned)gy < HH && (unsigned)gx < WW){
        float a[MID];
        #pragma unroll
        for (int o = 0; o < MID; o++) a[o] = 0.f;
        #pragma unroll
        for (int ky = 0; ky < 3; ky++){
          int yy = gy + ky - 1;
          if ((unsigned)yy >= HH) continue;
          #pragma unroll
          for (int kx = 0; kx < 3; kx++){
            int xx = gx + kx - 1;
            if ((unsigned)xx >= WW) continue;
            float m = (ab[(yy << 9) + xx] - mean) * inv;
            int k = ky * 3 + kx;
            #pragma unroll
            for (int o = 0; o < MID; o++) a[o] = fmaf(C[2 + o*9 + k], m, a[o]);
          }
        }
        unsigned pk[8];
        #pragma unroll
        for (int j = 0; j < 8; j++){
          float v0 = fmaxf(0.f, fmaf(a[2*j],   C[146 + 2*j],   C[162 + 2*j]));
          float v1 = fmaxf(0.f, fmaf(a[2*j+1], C[146 + 2*j+1], C[162 + 2*j+1]));
          pk[j] = packpair(v0, v1);
        }
        lo = make_uint4(pk[0], pk[1], pk[2], pk[3]);
        hi = make_uint4(pk[4], pk[5], pk[6], pk[7]);
      }
      PL[0][r*TC + p] = lo;
      PL[1][r*TC + p] = hi;
    }
  }
  __syncthreads();
  // ---- phase 2: conv2 via MFMA, B-operand from LDS (no bounds checks) ----
  int lane = tid & 63, wv = tid >> 6;
  int col = lane & 15, q = lane >> 4;
  int chSel = q & 1;
  bool hiTap = (q >= 2);
  uint4 wfrag[5];
  #pragma unroll
  for (int m = 0; m < 5; m++) wfrag[m] = ((const uint4*)wsB2)[m*64 + lane];
  float4 sc = *(const float4*)&C[288 + q*4];
  float4 bi = *(const float4*)&C[304 + q*4];
  #pragma unroll
  for (int rr = 0; rr < 2; rr++){
    int ly = wv*2 + rr;
    #pragma unroll
    for (int g = 0; g < 4; g++){
      int lx = g << 4;
      f32x4 cc = {0.f, 0.f, 0.f, 0.f};
      #pragma unroll
      for (int m = 0; m < 5; m++){
        const int ta = 2*m, tb = 2*m + 1;
        int dy = (hiTap ? tb/3 : ta/3) - 1;
        int dx = (hiTap ? tb%3 : ta%3) - 1;
        bool tv = hiTap ? (tb < 9) : true;
        int trow = ly + 2 + 2*dy;            // in [0,11]
        int tpx  = lx + 2 + col + 2*dx;      // in [0,67]
        U4B bv; bv.u = PL[chSel][trow*TC + tpx];
        if (!tv) bv.u = make_uint4(0u,0u,0u,0u);
        U4B wb; wb.u = wfrag[m];
        cc = __builtin_amdgcn_mfma_f32_16x16x32_bf16(wb.h, bv.h, cc, 0, 0, 0);
      }
      float v0 = fmaxf(0.f, fmaf(cc[0], sc.x, bi.x));
      float v1 = fmaxf(0.f, fmaf(cc[1], sc.y, bi.y));
      float v2 = fmaxf(0.f, fmaf(cc[2], sc.z, bi.z));
      float v3 = fmaxf(0.f, fmaf(cc[3], sc.w, bi.w));
      int gy = y0 + ly, gx = x0 + lx + col;
      h2[(size_t)((b << 18) | (gy << 9) | gx)*4 + q] =
          make_uint2(packpair(v0, v1), packpair(v2, v3));
    }
  }
}

// ---------- swapped MFMA conv core: A = weights, B = pixel patches (global) ----------
template<int DIL>
__device__ inline f32x4 convW(const uint4* __restrict__ hin, const uint4 wfrag[5],
                              int b, int y, int x0, int col, int q, f32x4 cc){
  int chSel = q & 1;
  bool hiTap = (q >= 2);
  #pragma unroll
  for (int m = 0; m < 5; m++){
    const int ta = 2*m, tb = 2*m + 1;
    int dy = (hiTap ? tb/3 : ta/3) - 1;
    int dx = (hiTap ? tb%3 : ta%3) - 1;
    bool tv = hiTap ? (tb < 9) : true;
    int yy = y + dy * DIL;
    int xx = x0 + col + dx * DIL;
    bool valid = tv && ((unsigned)yy < HH) && ((unsigned)xx < WW);
    U4B a; a.u = make_uint4(0u, 0u, 0u, 0u);
    if (valid) a.u = hin[(((unsigned)((b << 18) | (yy << 9) | xx)) << 1) | (unsigned)chSel];
    U4B bb; bb.u = wfrag[m];
    cc = __builtin_amdgcn_mfma_f32_16x16x32_bf16(bb.h, a.h, cc, 0, 0, 0);
  }
  return cc;
}

// ======== kernel 4: conv3 (dil 4, MFMA) + BN/ReLU + w4 MFMA + sigmoid + enhance ========
__global__ __launch_bounds__(256) void k_conv3m(const uint4* __restrict__ h2,
                                                const float* __restrict__ C,
                                                const unsigned* __restrict__ wsB3,
                                                const uint4* __restrict__ wsB4,
                                                const float* __restrict__ xal,
                                                float* __restrict__ out){
  __shared__ uint4 LB[4][640];               // 40 KB / block
  int lane = threadIdx.x & 63, wv = threadIdx.x >> 6;
  char* myL = (char*)LB[wv];
  unsigned short* Lk = (unsigned short*)(myL + 3072);   // kern rows, 56 shorts stride
  int w = blockIdx.x * 4 + wv;
  int base = w << 6;
  int b = base >> 18, rem = base & (HWSZ - 1);
  int y = rem >> 9, wx = rem & 511;
  uint4 wfrag[5];
  #pragma unroll
  for (int m = 0; m < 5; m++) wfrag[m] = ((const uint4*)wsB3)[m*64 + lane];
  uint4 bw[3];
  #pragma unroll
  for (int c = 0; c < 3; c++) bw[c] = wsB4[c*64 + lane];
  int col = lane & 15, q = lane >> 4;
  float4 sc = *(const float4*)&C[320 + q*4];
  float4 bi = *(const float4*)&C[336 + q*4];
  float cb = C[242];                                    // bias

  #pragma unroll
  for (int g = 0; g < 4; g++){
    f32x4 cc = {0.f, 0.f, 0.f, 0.f};
    cc = convW<4>(h2, wfrag, b, y, wx + g*16, col, q, cc);
    float v0 = fmaxf(0.f, fmaf(cc[0], sc.x, bi.x));
    float v1 = fmaxf(0.f, fmaf(cc[1], sc.y, bi.y));
    float v2 = fmaxf(0.f, fmaf(cc[2], sc.z, bi.z));
    float v3 = fmaxf(0.f, fmaf(cc[3], sc.w, bi.w));
    *(uint2*)(myL + (g*16 + col)*48 + q*8) = make_uint2(packpair(v0, v1), packpair(v2, v3));

    U4B a; a.u = make_uint4(0u, 0u, 0u, 0u);
    if (q < 2) a.u = *(const uint4*)(myL + (g*16 + col)*48 + q*16);
    #pragma unroll
    for (int c = 0; c < 3; c++){
      f32x4 aw = {cb, cb, cb, cb};
      U4B bb; bb.u = bw[c];
      aw = __builtin_amdgcn_mfma_f32_16x16x32_bf16(a.h, bb.h, aw, 0, 0, 0);
      #pragma unroll
      for (int r = 0; r < 4; r++){
        float e  = __expf(-aw[r]);
        float rc = __builtin_amdgcn_rcpf(1.f + e);
        float kern = fmaf(10.f, rc, 0.1f);
        unsigned u = __float_as_uint(kern) + 0x8000u;
        Lk[(g*16 + q*4 + r)*56 + c*16 + col] = (unsigned short)(u >> 16);
      }
    }
  }

  unsigned kvf[24];
  {
    const uint4* kp = (const uint4*)(myL + 3072 + lane*112);
    #pragma unroll
    for (int jj = 0; jj < 6; jj++){
      uint4 u = kp[jj];
      kvf[4*jj] = u.x; kvf[4*jj+1] = u.y; kvf[4*jj+2] = u.z; kvf[4*jj+3] = u.w;
    }
  }
  int px = wx + lane;
  bool mxl = (px > 0), mxr = (px < 511), mym = (y > 0), myp = (y < 511);
  bool msk[9] = { mym&&mxl, mym, mym&&mxr,
                  mxl,      true, mxr,
                  myp&&mxl, myp, myp&&mxr };
  int rowm = mym ? -2048 : 0;
  int rowp = myp ?  2048 : 0;
  int loff = mxl ? -4 : 0;
  int roff = mxr ?  4 : 0;
  const char* base0 = (const char*)(xal + ((size_t)(b*TT) << 18) + (y << 9) + px);
  #pragma unroll
  for (int t = 0; t < TT; t++){
    const char* pc = base0 + (size_t)t * (HWSZ*4);
    const char* pm = pc + rowm;
    const char* pp = pc + rowp;
    float xv[9];
    xv[0] = *(const float*)(pm + loff);
    xv[1] = *(const float*)(pm);
    xv[2] = *(const float*)(pm + roff);
    xv[3] = *(const float*)(pc + loff);
    xv[4] = *(const float*)(pc);
    xv[5] = *(const float*)(pc + roff);
    xv[6] = *(const float*)(pp + loff);
    xv[7] = *(const float*)(pp);
    xv[8] = *(const float*)(pp + roff);
    float ov = 0.f;
    #pragma unroll
    for (int k = 0; k < 9; k++){
      int n = t*9 + k;
      unsigned u = kvf[n >> 1];
      float kf = (n & 1) ? bhi(u) : blo(u);
      float kern = msk[k] ? kf : 0.f;
      ov = fmaf(kern, xv[k], ov);
    }
    out[((size_t)(b*TT + t) << 18) + (y << 9) + px] = ov;
  }
}

extern "C" void kernel_launch(void* const* d_in, const int* in_sizes, int n_in,
                              void* d_out, int out_size, void* d_ws, size_t ws_size,
                              hipStream_t stream){
  const float* xal = (const float*)d_in[0];
  const float* rd  = (const float*)d_in[1];
  const float* w1  = (const float*)d_in[2];
  const float* g1  = (const float*)d_in[3];
  const float* b1  = (const float*)d_in[4];
  const float* rm1 = (const float*)d_in[5];
  const float* rv1 = (const float*)d_in[6];
  const float* w2  = (const float*)d_in[7];
  const float* g2  = (const float*)d_in[8];
  const float* b2  = (const float*)d_in[9];
  const float* rm2 = (const float*)d_in[10];
  const float* rv2 = (const float*)d_in[11];
  const float* w3  = (const float*)d_in[12];
  const float* g3  = (const float*)d_in[13];
  const float* b3  = (const float*)d_in[14];
  const float* rm3 = (const float*)d_in[15];
  const float* rv3 = (const float*)d_in[16];
  const float* w4  = (const float*)d_in[17];
  const float* bias= (const float*)d_in[18];
  float* out = (float*)d_out;

  char* ws = (char*)d_ws;
  float2*   partial = (float2*)ws;                    // 16 KB
  float*    cst   = (float*)(ws + 16384);             // 352 floats used
  unsigned* wsB2  = (unsigned*)(ws + 32768);          // 5 KB
  unsigned* wsB3  = (unsigned*)(ws + 40960);          // 5 KB
  uint4*    wsB4  = (uint4*)(ws + 49152);             // 3 KB
  float*    acc   = (float*)(ws + 65536);             // 8 MB
  char*     h2    = (char*)(ws + 65536 + (size_t)NPIX*4);                     // 64 MB

  k_acc<<<2048, 256, 0, stream>>>(rd, (float4*)acc, partial);
  k_prep<<<1, 256, 0, stream>>>(partial, w1, w2, w3,
                                g1, b1, rm1, rv1,
                                g2, b2, rm2, rv2,
                                g3, b3, rm3, rv3, w4, bias, cst, wsB2, wsB3, wsB4);
  k_conv12<<<4096, 256, 0, stream>>>(acc, cst, wsB2, (uint2*)h2);
  k_conv3m<<<NPIX/256, 256, 0, stream>>>((const uint4*)h2, cst, wsB3, wsB4, xal, out);
}

// Round 8
// 260.784 us; speedup vs baseline: 2.6326x; 1.0446x over previous
//
#include <hip/hip_runtime.h>
#include <hip/hip_bf16.h>
#include <math.h>

#define HH 512
#define WW 512
#define BB 8
#define TT 5
#define MID 16
#define HWSZ (HH*WW)      /* 262144 = 2^18 */
#define NPIX (BB*HWSZ)    /* 2097152 */

typedef __attribute__((ext_vector_type(8))) short bf16x8;
typedef __attribute__((ext_vector_type(4))) float f32x4;

// ---------- bf16 helpers ----------
__device__ inline unsigned short f2bf(float f){          // RNE (used in prep only)
  unsigned u = __float_as_uint(f);
  u = u + 0x7fffu + ((u >> 16) & 1u);
  return (unsigned short)(u >> 16);
}
// fast round-half-up pack of two floats -> bf16 pair (low16 = a, high16 = b)
__device__ inline unsigned packpair(float a, float b){
  unsigned ua = __float_as_uint(a) + 0x8000u;
  unsigned ub = __float_as_uint(b) + 0x8000u;
  return __builtin_amdgcn_perm(ub, ua, 0x07060302u);
}
__device__ inline float blo(unsigned u){ return __uint_as_float(u << 16); }
__device__ inline float bhi(unsigned u){ return __uint_as_float(u & 0xffff0000u); }

union U4B { uint4 u; bf16x8 h; };

// ---------- consts layout (floats, in cst) ----------
// [0] mean  [1] inv_std
// [2..145]   w1eff[16][9]
// [146..161] sc1   [162..177] bi1
// [242] bias
// [288..303] sc2a  [304..319] bi2a
// [320..335] sc3a  [336..351] bi3a

// ================= kernel 1: accumulate |raw_diff| + per-block partial stats =================
__global__ __launch_bounds__(256) void k_acc(const float* __restrict__ rd,
                                             float4* __restrict__ acc,
                                             float2* __restrict__ partial){
  int t = blockIdx.x * 256 + threadIdx.x;   // 0..524287
  int i = t << 2;
  int b = i >> 18, p = i & (HWSZ - 1);
  const float* base = rd + (size_t)b * 4 * HWSZ + p;
  float4 f0 = *(const float4*)(base);
  float4 f1 = *(const float4*)(base + HWSZ);
  float4 f2 = *(const float4*)(base + 2*HWSZ);
  float4 f3 = *(const float4*)(base + 3*HWSZ);
  float4 s4;
  s4.x = fabsf(f0.x) + fabsf(f1.x) + fabsf(f2.x) + fabsf(f3.x);
  s4.y = fabsf(f0.y) + fabsf(f1.y) + fabsf(f2.y) + fabsf(f3.y);
  s4.z = fabsf(f0.z) + fabsf(f1.z) + fabsf(f2.z) + fabsf(f3.z);
  s4.w = fabsf(f0.w) + fabsf(f1.w) + fabsf(f2.w) + fabsf(f3.w);
  acc[t] = s4;
  float s  = s4.x + s4.y + s4.z + s4.w;
  float s2 = s4.x*s4.x + s4.y*s4.y + s4.z*s4.z + s4.w*s4.w;
  #pragma unroll
  for (int off = 32; off; off >>= 1){
    s  += __shfl_down(s,  off);
    s2 += __shfl_down(s2, off);
  }
  __shared__ float ls[4], ls2[4];
  int lane = threadIdx.x & 63, wid = threadIdx.x >> 6;
  if (lane == 0){ ls[wid] = s; ls2[wid] = s2; }
  __syncthreads();
  if (threadIdx.x == 0)
    partial[blockIdx.x] = make_float2(ls[0]+ls[1]+ls[2]+ls[3],
                                      ls2[0]+ls2[1]+ls2[2]+ls2[3]);
}

// ================= kernel 2: reduce partials + folded weights / MFMA frags =================
__global__ __launch_bounds__(256) void k_prep(const float2* __restrict__ partial,
    const float* __restrict__ w1, const float* __restrict__ w2, const float* __restrict__ w3,
    const float* __restrict__ g1, const float* __restrict__ b1, const float* __restrict__ rm1, const float* __restrict__ rv1,
    const float* __restrict__ g2, const float* __restrict__ b2, const float* __restrict__ rm2, const float* __restrict__ rv2,
    const float* __restrict__ g3, const float* __restrict__ b3, const float* __restrict__ rm3, const float* __restrict__ rv3,
    const float* __restrict__ w4, const float* __restrict__ bias0,
    float* __restrict__ cst, unsigned* __restrict__ wsB2, unsigned* __restrict__ wsB3,
    uint4* __restrict__ wsB4){
  int t = threadIdx.x;
  double s = 0.0, s2 = 0.0;
  for (int j = t; j < 2048; j += 256){
    float2 v = partial[j];
    s += (double)v.x; s2 += (double)v.y;
  }
  #pragma unroll
  for (int off = 32; off; off >>= 1){
    s  += __shfl_down(s,  off);
    s2 += __shfl_down(s2, off);
  }
  __shared__ double ds[4], ds2[4];
  int lane = t & 63, wid = t >> 6;
  if (lane == 0){ ds[wid] = s; ds2[wid] = s2; }
  __syncthreads();
  if (t == 0){
    double S  = ds[0]+ds[1]+ds[2]+ds[3];
    double S2 = ds2[0]+ds2[1]+ds2[2]+ds2[3];
    double n = (double)NPIX;
    double mean = S / n;
    double var  = (S2 - n * mean * mean) / (n - 1.0);
    double sd   = sqrt(var);
    cst[0] = (float)mean;
    cst[1] = (float)(1.0 / (sd + 1e-6));
    cst[242] = bias0[0];
  }
  if (t < 144){
    int c = t / 9, k = t % 9;
    float sw = 0.f;
    for (int f = 0; f < TT; f++) sw += w1[c*45 + f*9 + k];
    cst[2 + t] = sw;
  }
  if (t < 16){
    float s1 = g1[t] * rsqrtf(rv1[t] + 1e-5f);
    cst[146 + t] = s1; cst[162 + t] = b1[t] - rm1[t] * s1;
    float c2 = g2[t] * rsqrtf(rv2[t] + 1e-5f);
    cst[288 + t] = c2; cst[304 + t] = b2[t] - rm2[t] * c2;
    float c3 = g3[t] * rsqrtf(rv3[t] + 1e-5f);
    cst[320 + t] = c3; cst[336 + t] = b3[t] - rm3[t] * c3;
  }
  // conv-weight fragments for 16x16x32 bf16 MFMA (A operand): lane holds
  // [out=lane&15][k=(lane>>4)*8+j], k -> tap = 2m + (k>>4), ci = k&15; tap 9 zero.
  for (int it = 0; it < 5; it++){
    int idx = it * 256 + t;          // 0..1279
    int m = idx >> 8, rem = idx & 255;
    int L = rem >> 2, jj = rem & 3;
    int out = L & 15, q = L >> 4;
    unsigned v2 = 0, v3 = 0;
    #pragma unroll
    for (int h = 0; h < 2; h++){
      int j = 2*jj + h;
      int k = q*8 + j;
      int tap = 2*m + (k >> 4);
      int ci = k & 15;
      unsigned bv2 = 0, bv3 = 0;
      if (tap < 9){
        bv2 = f2bf(w2[out*144 + ci*9 + tap]);
        bv3 = f2bf(w3[out*144 + ci*9 + tap]);
      }
      v2 |= bv2 << (16*h);
      v3 |= bv3 << (16*h);
    }
    wsB2[idx] = v2; wsB3[idx] = v3;
  }
  // B-fragments for w4 16x16x32 MFMA (K: ch 0..15 real, 16..31 zero), 3 N-chunks.
  if (t < 192){
    int c = t >> 6, L = t & 63;
    int n = L & 15, q = L >> 4;
    int o = c*16 + n;
    unsigned vv[4];
    #pragma unroll
    for (int jj = 0; jj < 4; jj++){
      unsigned pk = 0;
      #pragma unroll
      for (int h = 0; h < 2; h++){
        int j = 2*jj + h, kci = q*8 + j;
        unsigned bv = 0;
        if (kci < 16 && o < 45) bv = f2bf(w4[o*16 + kci]);
        pk |= bv << (16*h);
      }
      vv[jj] = pk;
    }
    wsB4[c*64 + L] = make_uint4(vv[0], vv[1], vv[2], vv[3]);
  }
}

// ======== kernel 3: FUSED conv1 (from LDS acc tile) + conv2 (MFMA from LDS) ========
// Block covers 64x8 output px. acc tile AT: 14 rows x 72 cols normalized f32
// (halo = 0 == conv's zero-pad of the normalized motion). h1 tile PL: 68x12.
#define TR 12
#define TC 68
__global__ __launch_bounds__(256) void k_conv12(const float* __restrict__ acc,
                                                const float* __restrict__ C,
                                                const unsigned* __restrict__ wsB2,
                                                uint2* __restrict__ h2){
  __shared__ float AT[14*72];             // 4032 B
  __shared__ uint4 PL[2][TR*TC];          // 26112 B
  int tid = threadIdx.x;
  int blk = blockIdx.x;                    // 8 xt | 64 yt | 8 b
  int xt = blk & 7, yt = (blk >> 3) & 63, b = blk >> 9;
  int y0 = yt << 3, x0 = xt << 6;
  float mean = C[0], inv = C[1];
  const float* ab = acc + ((size_t)b << 18);
  // ---- phase 0: stage normalized acc tile (coalesced), halo/pad = 0 ----
  #pragma unroll
  for (int it = 0; it < 4; it++){
    int idx = it*256 + tid;
    if (idx < 14*72){
      int r = (idx * 1821) >> 17;          // idx/72 exact for idx<1008
      int p = idx - r*72;
      int gy = y0 - 3 + r, gx = x0 - 3 + p;
      float v = 0.f;
      if ((unsigned)gy < HH && (unsigned)gx < WW)
        v = (ab[(gy << 9) + gx] - mean) * inv;
      AT[idx] = v;
    }
  }
  __syncthreads();
  // ---- phase 1: conv1 + BN + ReLU from LDS into PL; out-of-image h1 = 0 ----
  #pragma unroll
  for (int it = 0; it < 4; it++){
    int i = it*256 + tid;
    if (i < TR*TC){
      int r2 = (i * 241) >> 14;            // i/68 exact for i<816
      int p2 = i - r2*TC;
      int gy = y0 - 2 + r2, gx = x0 - 2 + p2;
      uint4 lo = make_uint4(0u,0u,0u,0u), hi = lo;
      if ((unsigned)gy < HH && (unsigned)gx < WW){
        float a[MID];
        #pragma unroll
        for (int o = 0; o < MID; o++) a[o] = 0.f;
        #pragma unroll
        for (int ky = 0; ky < 3; ky++){
          #pragma unroll
          for (int kx = 0; kx < 3; kx++){
            float m = AT[(r2 + ky)*72 + (p2 + kx)];
            int k = ky * 3 + kx;
            #pragma unroll
            for (int o = 0; o < MID; o++) a[o] = fmaf(C[2 + o*9 + k], m, a[o]);
          }
        }
        unsigned pk[8];
        #pragma unroll
        for (int j = 0; j < 8; j++){
          float v0 = fmaxf(0.f, fmaf(a[2*j],   C[146 + 2*j],   C[162 + 2*j]));
          float v1 = fmaxf(0.f, fmaf(a[2*j+1], C[146 + 2*j+1], C[162 + 2*j+1]));
          pk[j] = packpair(v0, v1);
        }
        lo = make_uint4(pk[0], pk[1], pk[2], pk[3]);
        hi = make_uint4(pk[4], pk[5], pk[6], pk[7]);
      }
      PL[0][r2*TC + p2] = lo;
      PL[1][r2*TC + p2] = hi;
    }
  }
  __syncthreads();
  // ---- phase 2: conv2 via MFMA, B-operand from LDS (no bounds checks) ----
  int lane = tid & 63, wv = tid >> 6;
  int col = lane & 15, q = lane >> 4;
  int chSel = q & 1;
  bool hiTap = (q >= 2);
  uint4 wfrag[5];
  #pragma unroll
  for (int m = 0; m < 5; m++) wfrag[m] = ((const uint4*)wsB2)[m*64 + lane];
  float4 sc = *(const float4*)&C[288 + q*4];
  float4 bi = *(const float4*)&C[304 + q*4];
  #pragma unroll
  for (int rr = 0; rr < 2; rr++){
    int ly = wv*2 + rr;
    #pragma unroll
    for (int g = 0; g < 4; g++){
      int lx = g << 4;
      f32x4 cc = {0.f, 0.f, 0.f, 0.f};
      #pragma unroll
      for (int m = 0; m < 5; m++){
        const int ta = 2*m, tb = 2*m + 1;
        int dy = (hiTap ? tb/3 : ta/3) - 1;
        int dx = (hiTap ? tb%3 : ta%3) - 1;
        bool tv = hiTap ? (tb < 9) : true;
        int trow = ly + 2 + 2*dy;            // in [0,11]
        int tpx  = lx + 2 + col + 2*dx;      // in [0,67]
        U4B bv; bv.u = PL[chSel][trow*TC + tpx];
        if (!tv) bv.u = make_uint4(0u,0u,0u,0u);
        U4B wb; wb.u = wfrag[m];
        cc = __builtin_amdgcn_mfma_f32_16x16x32_bf16(wb.h, bv.h, cc, 0, 0, 0);
      }
      float v0 = fmaxf(0.f, fmaf(cc[0], sc.x, bi.x));
      float v1 = fmaxf(0.f, fmaf(cc[1], sc.y, bi.y));
      float v2 = fmaxf(0.f, fmaf(cc[2], sc.z, bi.z));
      float v3 = fmaxf(0.f, fmaf(cc[3], sc.w, bi.w));
      int gy = y0 + ly, gx = x0 + lx + col;
      h2[(size_t)((b << 18) | (gy << 9) | gx)*4 + q] =
          make_uint2(packpair(v0, v1), packpair(v2, v3));
    }
  }
}

// ---------- swapped MFMA conv core: A = weights, B = pixel patches (global) ----------
template<int DIL>
__device__ inline f32x4 convW(const uint4* __restrict__ hin, const uint4 wfrag[5],
                              int b, int y, int x0, int col, int q, f32x4 cc){
  int chSel = q & 1;
  bool hiTap = (q >= 2);
  #pragma unroll
  for (int m = 0; m < 5; m++){
    const int ta = 2*m, tb = 2*m + 1;
    int dy = (hiTap ? tb/3 : ta/3) - 1;
    int dx = (hiTap ? tb%3 : ta%3) - 1;
    bool tv = hiTap ? (tb < 9) : true;
    int yy = y + dy * DIL;
    int xx = x0 + col + dx * DIL;
    bool valid = tv && ((unsigned)yy < HH) && ((unsigned)xx < WW);
    U4B a; a.u = make_uint4(0u, 0u, 0u, 0u);
    if (valid) a.u = hin[(((unsigned)((b << 18) | (yy << 9) | xx)) << 1) | (unsigned)chSel];
    U4B bb; bb.u = wfrag[m];
    cc = __builtin_amdgcn_mfma_f32_16x16x32_bf16(bb.h, a.h, cc, 0, 0, 0);
  }
  return cc;
}

// ======== kernel 4: conv3 (dil 4, MFMA) + BN/ReLU + w4 MFMA + sigmoid + enhance ========
// Per-wave LDS: kern only, 64 px rows x 96 B (48 bf16) = 6144 B. h3 hand-off
// from stage-1 C-layout to stage-2 A-layout is done with 4 wave shuffles.
__global__ __launch_bounds__(256) void k_conv3m(const uint4* __restrict__ h2,
                                                const float* __restrict__ C,
                                                const unsigned* __restrict__ wsB3,
                                                const uint4* __restrict__ wsB4,
                                                const float* __restrict__ xal,
                                                float* __restrict__ out){
  __shared__ uint4 LB[4][384];               // 24576 B / block
  int lane = threadIdx.x & 63, wv = threadIdx.x >> 6;
  char* myL = (char*)LB[wv];
  unsigned short* Lk = (unsigned short*)myL;            // kern rows, 48 shorts stride
  int w = blockIdx.x * 4 + wv;
  int base = w << 6;
  int b = base >> 18, rem = base & (HWSZ - 1);
  int y = rem >> 9, wx = rem & 511;
  uint4 wfrag[5];
  #pragma unroll
  for (int m = 0; m < 5; m++) wfrag[m] = ((const uint4*)wsB3)[m*64 + lane];
  uint4 bw[3];
  #pragma unroll
  for (int c = 0; c < 3; c++) bw[c] = wsB4[c*64 + lane];
  int col = lane & 15, q = lane >> 4;
  float4 sc = *(const float4*)&C[320 + q*4];
  float4 bi = *(const float4*)&C[336 + q*4];
  float cb = C[242];                                    // bias
  int src0 = col + q*32;                                // h3 shuffle sources (q<2)
  int src1 = src0 + 16;

  #pragma unroll
  for (int g = 0; g < 4; g++){
    // ---- stage 1: conv3 (C: col=px, row=ch) + BN + ReLU, packed in-register ----
    f32x4 cc = {0.f, 0.f, 0.f, 0.f};
    cc = convW<4>(h2, wfrag, b, y, wx + g*16, col, q, cc);
    float v0 = fmaxf(0.f, fmaf(cc[0], sc.x, bi.x));
    float v1 = fmaxf(0.f, fmaf(cc[1], sc.y, bi.y));
    float v2 = fmaxf(0.f, fmaf(cc[2], sc.z, bi.z));
    float v3 = fmaxf(0.f, fmaf(cc[3], sc.w, bi.w));
    int pk01 = (int)packpair(v0, v1);      // ch q*4, q*4+1 of pixel col
    int pk23 = (int)packpair(v2, v3);      // ch q*4+2, q*4+3

    // ---- C-layout -> A-layout via shuffles: lane(col,q<2) = ch q*8..q*8+7 ----
    U4B a;
    a.u.x = (unsigned)__shfl(pk01, src0);
    a.u.y = (unsigned)__shfl(pk23, src0);
    a.u.z = (unsigned)__shfl(pk01, src1);
    a.u.w = (unsigned)__shfl(pk23, src1);
    if (q >= 2) a.u = make_uint4(0u,0u,0u,0u);

    // ---- stage 2: w4 MFMA (K=16 padded to 32) + sigmoid -> kern LDS ----
    #pragma unroll
    for (int c = 0; c < 3; c++){
      f32x4 aw = {cb, cb, cb, cb};
      U4B bb; bb.u = bw[c];
      aw = __builtin_amdgcn_mfma_f32_16x16x32_bf16(a.h, bb.h, aw, 0, 0, 0);
      #pragma unroll
      for (int r = 0; r < 4; r++){
        float e  = __expf(-aw[r]);
        float rc = __builtin_amdgcn_rcpf(1.f + e);
        float kern = fmaf(10.f, rc, 0.1f);
        unsigned u = __float_as_uint(kern) + 0x8000u;
        Lk[(g*16 + q*4 + r)*48 + c*16 + col] = (unsigned short)(u >> 16);
      }
    }
  }

  // ---- stage 3: lane owns pixel (wx+lane); 45 kern x patch FMAs ----
  unsigned kvf[24];
  {
    const uint4* kp = (const uint4*)(myL + lane*96);
    #pragma unroll
    for (int jj = 0; jj < 6; jj++){
      uint4 u = kp[jj];
      kvf[4*jj] = u.x; kvf[4*jj+1] = u.y; kvf[4*jj+2] = u.z; kvf[4*jj+3] = u.w;
    }
  }
  int px = wx + lane;
  bool mxl = (px > 0), mxr = (px < 511), mym = (y > 0), myp = (y < 511);
  bool msk[9] = { mym&&mxl, mym, mym&&mxr,
                  mxl,      true, mxr,
                  myp&&mxl, myp, myp&&mxr };
  int rowm = mym ? -2048 : 0;
  int rowp = myp ?  2048 : 0;
  int loff = mxl ? -4 : 0;
  int roff = mxr ?  4 : 0;
  const char* base0 = (const char*)(xal + ((size_t)(b*TT) << 18) + (y << 9) + px);
  #pragma unroll
  for (int t = 0; t < TT; t++){
    const char* pc = base0 + (size_t)t * (HWSZ*4);
    const char* pm = pc + rowm;
    const char* pp = pc + rowp;
    float xv[9];
    xv[0] = *(const float*)(pm + loff);
    xv[1] = *(const float*)(pm);
    xv[2] = *(const float*)(pm + roff);
    xv[3] = *(const float*)(pc + loff);
    xv[4] = *(const float*)(pc);
    xv[5] = *(const float*)(pc + roff);
    xv[6] = *(const float*)(pp + loff);
    xv[7] = *(const float*)(pp);
    xv[8] = *(const float*)(pp + roff);
    float ov = 0.f;
    #pragma unroll
    for (int k = 0; k < 9; k++){
      int n = t*9 + k;
      unsigned u = kvf[n >> 1];
      float kf = (n & 1) ? bhi(u) : blo(u);
      float kern = msk[k] ? kf : 0.f;
      ov = fmaf(kern, xv[k], ov);
    }
    out[((size_t)(b*TT + t) << 18) + (y << 9) + px] = ov;
  }
}

extern "C" void kernel_launch(void* const* d_in, const int* in_sizes, int n_in,
                              void* d_out, int out_size, void* d_ws, size_t ws_size,
                              hipStream_t stream){
  const float* xal = (const float*)d_in[0];
  const float* rd  = (const float*)d_in[1];
  const float* w1  = (const float*)d_in[2];
  const float* g1  = (const float*)d_in[3];
  const float* b1  = (const float*)d_in[4];
  const float* rm1 = (const float*)d_in[5];
  const float* rv1 = (const float*)d_in[6];
  const float* w2  = (const float*)d_in[7];
  const float* g2  = (const float*)d_in[8];
  const float* b2  = (const float*)d_in[9];
  const float* rm2 = (const float*)d_in[10];
  const float* rv2 = (const float*)d_in[11];
  const float* w3  = (const float*)d_in[12];
  const float* g3  = (const float*)d_in[13];
  const float* b3  = (const float*)d_in[14];
  const float* rm3 = (const float*)d_in[15];
  const float* rv3 = (const float*)d_in[16];
  const float* w4  = (const float*)d_in[17];
  const float* bias= (const float*)d_in[18];
  float* out = (float*)d_out;

  char* ws = (char*)d_ws;
  float2*   partial = (float2*)ws;                    // 16 KB
  float*    cst   = (float*)(ws + 16384);             // 352 floats used
  unsigned* wsB2  = (unsigned*)(ws + 32768);          // 5 KB
  unsigned* wsB3  = (unsigned*)(ws + 40960);          // 5 KB
  uint4*    wsB4  = (uint4*)(ws + 49152);             // 3 KB
  float*    acc   = (float*)(ws + 65536);             // 8 MB
  char*     h2    = (char*)(ws + 65536 + (size_t)NPIX*4);                     // 64 MB

  k_acc<<<2048, 256, 0, stream>>>(rd, (float4*)acc, partial);
  k_prep<<<1, 256, 0, stream>>>(partial, w1, w2, w3,
                                g1, b1, rm1, rv1,
                                g2, b2, rm2, rv2,
                                g3, b3, rm3, rv3, w4, bias, cst, wsB2, wsB3, wsB4);
  k_conv12<<<4096, 256, 0, stream>>>(acc, cst, wsB2, (uint2*)h2);
  k_conv3m<<<NPIX/256, 256, 0, stream>>>((const uint4*)h2, cst, wsB3, wsB4, xal, out);
}

// Round 9
// 252.697 us; speedup vs baseline: 2.7168x; 1.0320x over previous
//
#include <hip/hip_runtime.h>
#include <hip/hip_bf16.h>
#include <math.h>

#define HH 512
#define WW 512
#define BB 8
#define TT 5
#define MID 16
#define HWSZ (HH*WW)      /* 262144 = 2^18 */
#define NPIX (BB*HWSZ)    /* 2097152 */

typedef __attribute__((ext_vector_type(8))) short bf16x8;
typedef __attribute__((ext_vector_type(4))) float f32x4;

// ---------- bf16 helpers ----------
__device__ inline unsigned short f2bf(float f){          // RNE (used in prep only)
  unsigned u = __float_as_uint(f);
  u = u + 0x7fffu + ((u >> 16) & 1u);
  return (unsigned short)(u >> 16);
}
// fast round-half-up pack of two floats -> bf16 pair (low16 = a, high16 = b)
__device__ inline unsigned packpair(float a, float b){
  unsigned ua = __float_as_uint(a) + 0x8000u;
  unsigned ub = __float_as_uint(b) + 0x8000u;
  return __builtin_amdgcn_perm(ub, ua, 0x07060302u);
}
__device__ inline float blo(unsigned u){ return __uint_as_float(u << 16); }
__device__ inline float bhi(unsigned u){ return __uint_as_float(u & 0xffff0000u); }

union U4B { uint4 u; bf16x8 h; };

// ---------- consts layout (floats, in cst) ----------
// [0] mean  [1] inv_std
// [2..145]   w1eff[16][9]
// [146..161] sc1   [162..177] bi1
// [242] bias
// [288..303] sc2a  [304..319] bi2a
// [320..335] sc3a  [336..351] bi3a

// ================= kernel 1: accumulate |raw_diff| + per-block partial stats =================
__global__ __launch_bounds__(256) void k_acc(const float* __restrict__ rd,
                                             float4* __restrict__ acc,
                                             float2* __restrict__ partial){
  int t = blockIdx.x * 256 + threadIdx.x;   // 0..524287
  int i = t << 2;
  int b = i >> 18, p = i & (HWSZ - 1);
  const float* base = rd + (size_t)b * 4 * HWSZ + p;
  float4 f0 = *(const float4*)(base);
  float4 f1 = *(const float4*)(base + HWSZ);
  float4 f2 = *(const float4*)(base + 2*HWSZ);
  float4 f3 = *(const float4*)(base + 3*HWSZ);
  float4 s4;
  s4.x = fabsf(f0.x) + fabsf(f1.x) + fabsf(f2.x) + fabsf(f3.x);
  s4.y = fabsf(f0.y) + fabsf(f1.y) + fabsf(f2.y) + fabsf(f3.y);
  s4.z = fabsf(f0.z) + fabsf(f1.z) + fabsf(f2.z) + fabsf(f3.z);
  s4.w = fabsf(f0.w) + fabsf(f1.w) + fabsf(f2.w) + fabsf(f3.w);
  acc[t] = s4;
  float s  = s4.x + s4.y + s4.z + s4.w;
  float s2 = s4.x*s4.x + s4.y*s4.y + s4.z*s4.z + s4.w*s4.w;
  #pragma unroll
  for (int off = 32; off; off >>= 1){
    s  += __shfl_down(s,  off);
    s2 += __shfl_down(s2, off);
  }
  __shared__ float ls[4], ls2[4];
  int lane = threadIdx.x & 63, wid = threadIdx.x >> 6;
  if (lane == 0){ ls[wid] = s; ls2[wid] = s2; }
  __syncthreads();
  if (threadIdx.x == 0)
    partial[blockIdx.x] = make_float2(ls[0]+ls[1]+ls[2]+ls[3],
                                      ls2[0]+ls2[1]+ls2[2]+ls2[3]);
}

// ================= kernel 2: reduce partials + folded weights / MFMA frags =================
__global__ __launch_bounds__(256) void k_prep(const float2* __restrict__ partial,
    const float* __restrict__ w1, const float* __restrict__ w2, const float* __restrict__ w3,
    const float* __restrict__ g1, const float* __restrict__ b1, const float* __restrict__ rm1, const float* __restrict__ rv1,
    const float* __restrict__ g2, const float* __restrict__ b2, const float* __restrict__ rm2, const float* __restrict__ rv2,
    const float* __restrict__ g3, const float* __restrict__ b3, const float* __restrict__ rm3, const float* __restrict__ rv3,
    const float* __restrict__ w4, const float* __restrict__ bias0,
    float* __restrict__ cst, unsigned* __restrict__ wsB2, unsigned* __restrict__ wsB3,
    uint4* __restrict__ wsB4){
  int t = threadIdx.x;
  double s = 0.0, s2 = 0.0;
  for (int j = t; j < 2048; j += 256){
    float2 v = partial[j];
    s += (double)v.x; s2 += (double)v.y;
  }
  #pragma unroll
  for (int off = 32; off; off >>= 1){
    s  += __shfl_down(s,  off);
    s2 += __shfl_down(s2, off);
  }
  __shared__ double ds[4], ds2[4];
  int lane = t & 63, wid = t >> 6;
  if (lane == 0){ ds[wid] = s; ds2[wid] = s2; }
  __syncthreads();
  if (t == 0){
    double S  = ds[0]+ds[1]+ds[2]+ds[3];
    double S2 = ds2[0]+ds2[1]+ds2[2]+ds2[3];
    double n = (double)NPIX;
    double mean = S / n;
    double var  = (S2 - n * mean * mean) / (n - 1.0);
    double sd   = sqrt(var);
    cst[0] = (float)mean;
    cst[1] = (float)(1.0 / (sd + 1e-6));
    cst[242] = bias0[0];
  }
  if (t < 144){
    int c = t / 9, k = t % 9;
    float sw = 0.f;
    for (int f = 0; f < TT; f++) sw += w1[c*45 + f*9 + k];
    cst[2 + t] = sw;
  }
  if (t < 16){
    float s1 = g1[t] * rsqrtf(rv1[t] + 1e-5f);
    cst[146 + t] = s1; cst[162 + t] = b1[t] - rm1[t] * s1;
    float c2 = g2[t] * rsqrtf(rv2[t] + 1e-5f);
    cst[288 + t] = c2; cst[304 + t] = b2[t] - rm2[t] * c2;
    float c3 = g3[t] * rsqrtf(rv3[t] + 1e-5f);
    cst[320 + t] = c3; cst[336 + t] = b3[t] - rm3[t] * c3;
  }
  // conv-weight fragments for 16x16x32 bf16 MFMA (A operand): lane holds
  // [out=lane&15][k=(lane>>4)*8+j], k -> tap = 2m + (k>>4), ci = k&15; tap 9 ZERO
  // (the zero weights are what make data-side tap-9 masking unnecessary).
  for (int it = 0; it < 5; it++){
    int idx = it * 256 + t;          // 0..1279
    int m = idx >> 8, rem = idx & 255;
    int L = rem >> 2, jj = rem & 3;
    int out = L & 15, q = L >> 4;
    unsigned v2 = 0, v3 = 0;
    #pragma unroll
    for (int h = 0; h < 2; h++){
      int j = 2*jj + h;
      int k = q*8 + j;
      int tap = 2*m + (k >> 4);
      int ci = k & 15;
      unsigned bv2 = 0, bv3 = 0;
      if (tap < 9){
        bv2 = f2bf(w2[out*144 + ci*9 + tap]);
        bv3 = f2bf(w3[out*144 + ci*9 + tap]);
      }
      v2 |= bv2 << (16*h);
      v3 |= bv3 << (16*h);
    }
    wsB2[idx] = v2; wsB3[idx] = v3;
  }
  // B-fragments for w4 16x16x32 MFMA (K: ch 0..15 real, 16..31 ZERO), 3 N-chunks.
  if (t < 192){
    int c = t >> 6, L = t & 63;
    int n = L & 15, q = L >> 4;
    int o = c*16 + n;
    unsigned vv[4];
    #pragma unroll
    for (int jj = 0; jj < 4; jj++){
      unsigned pk = 0;
      #pragma unroll
      for (int h = 0; h < 2; h++){
        int j = 2*jj + h, kci = q*8 + j;
        unsigned bv = 0;
        if (kci < 16 && o < 45) bv = f2bf(w4[o*16 + kci]);
        pk |= bv << (16*h);
      }
      vv[jj] = pk;
    }
    wsB4[c*64 + L] = make_uint4(vv[0], vv[1], vv[2], vv[3]);
  }
}

// ======== kernel 3: FUSED conv1 (from LDS acc tile) + conv2 (MFMA from LDS) ========
#define TR 12
#define TC 68
__global__ __launch_bounds__(256) void k_conv12(const float* __restrict__ acc,
                                                const float* __restrict__ C,
                                                const unsigned* __restrict__ wsB2,
                                                uint2* __restrict__ h2){
  __shared__ float AT[14*72];             // 4032 B
  __shared__ uint4 PL[2][TR*TC];          // 26112 B
  int tid = threadIdx.x;
  int blk = blockIdx.x;                    // 8 xt | 64 yt | 8 b
  int xt = blk & 7, yt = (blk >> 3) & 63, b = blk >> 9;
  int y0 = yt << 3, x0 = xt << 6;
  float mean = C[0], inv = C[1];
  const float* ab = acc + ((size_t)b << 18);
  // ---- phase 0: stage normalized acc tile (coalesced), halo/pad = 0 ----
  #pragma unroll
  for (int it = 0; it < 4; it++){
    int idx = it*256 + tid;
    if (idx < 14*72){
      int r = (idx * 1821) >> 17;          // idx/72 exact for idx<1008
      int p = idx - r*72;
      int gy = y0 - 3 + r, gx = x0 - 3 + p;
      float v = 0.f;
      if ((unsigned)gy < HH && (unsigned)gx < WW)
        v = (ab[(gy << 9) + gx] - mean) * inv;
      AT[idx] = v;
    }
  }
  __syncthreads();
  // ---- phase 1: conv1 + BN + ReLU from LDS into PL; out-of-image h1 = 0 ----
  #pragma unroll
  for (int it = 0; it < 4; it++){
    int i = it*256 + tid;
    if (i < TR*TC){
      int r2 = (i * 241) >> 14;            // i/68 exact for i<816
      int p2 = i - r2*TC;
      int gy = y0 - 2 + r2, gx = x0 - 2 + p2;
      uint4 lo = make_uint4(0u,0u,0u,0u), hi = lo;
      if ((unsigned)gy < HH && (unsigned)gx < WW){
        float a[MID];
        #pragma unroll
        for (int o = 0; o < MID; o++) a[o] = 0.f;
        #pragma unroll
        for (int ky = 0; ky < 3; ky++){
          #pragma unroll
          for (int kx = 0; kx < 3; kx++){
            float m = AT[(r2 + ky)*72 + (p2 + kx)];
            int k = ky * 3 + kx;
            #pragma unroll
            for (int o = 0; o < MID; o++) a[o] = fmaf(C[2 + o*9 + k], m, a[o]);
          }
        }
        unsigned pk[8];
        #pragma unroll
        for (int j = 0; j < 8; j++){
          float v0 = fmaxf(0.f, fmaf(a[2*j],   C[146 + 2*j],   C[162 + 2*j]));
          float v1 = fmaxf(0.f, fmaf(a[2*j+1], C[146 + 2*j+1], C[162 + 2*j+1]));
          pk[j] = packpair(v0, v1);
        }
        lo = make_uint4(pk[0], pk[1], pk[2], pk[3]);
        hi = make_uint4(pk[4], pk[5], pk[6], pk[7]);
      }
      PL[0][r2*TC + p2] = lo;
      PL[1][r2*TC + p2] = hi;
    }
  }
  __syncthreads();
  // ---- phase 2: conv2 via MFMA, B-operand from LDS (tap-9 zeroed by weights) ----
  int lane = tid & 63, wv = tid >> 6;
  int col = lane & 15, q = lane >> 4;
  int chSel = q & 1;
  bool hiTap = (q >= 2);
  uint4 wfrag[5];
  #pragma unroll
  for (int m = 0; m < 5; m++) wfrag[m] = ((const uint4*)wsB2)[m*64 + lane];
  float4 sc = *(const float4*)&C[288 + q*4];
  float4 bi = *(const float4*)&C[304 + q*4];
  #pragma unroll
  for (int rr = 0; rr < 2; rr++){
    int ly = wv*2 + rr;
    #pragma unroll
    for (int g = 0; g < 4; g++){
      int lx = g << 4;
      f32x4 cc = {0.f, 0.f, 0.f, 0.f};
      #pragma unroll
      for (int m = 0; m < 5; m++){
        const int ta = 2*m, tb = (2*m + 1 > 8) ? 8 : (2*m + 1);  // tap9 -> tap8 addr (weight=0)
        int dy = (hiTap ? tb/3 : ta/3) - 1;
        int dx = (hiTap ? tb%3 : ta%3) - 1;
        int trow = ly + 2 + 2*dy;            // in [0,11]
        int tpx  = lx + 2 + col + 2*dx;      // in [0,67]
        U4B bv; bv.u = PL[chSel][trow*TC + tpx];
        U4B wb; wb.u = wfrag[m];
        cc = __builtin_amdgcn_mfma_f32_16x16x32_bf16(wb.h, bv.h, cc, 0, 0, 0);
      }
      float v0 = fmaxf(0.f, fmaf(cc[0], sc.x, bi.x));
      float v1 = fmaxf(0.f, fmaf(cc[1], sc.y, bi.y));
      float v2 = fmaxf(0.f, fmaf(cc[2], sc.z, bi.z));
      float v3 = fmaxf(0.f, fmaf(cc[3], sc.w, bi.w));
      int gy = y0 + ly, gx = x0 + lx + col;
      h2[(size_t)((b << 18) | (gy << 9) | gx)*4 + q] =
          make_uint2(packpair(v0, v1), packpair(v2, v3));
    }
  }
}

// ---------- conv3 MFMA core: A = weights, B = pixel patches (global) ----------
// EDGE=false: no masking at all (caller guarantees all tap addresses in-bounds;
// tap 9 reads tap 8's address, its weights are zero).
template<bool EDGE>
__device__ inline f32x4 convW4(const uint4* __restrict__ hin, const uint4 wfrag[5],
                               int b, int y, int x0, int col, int q, f32x4 cc){
  int chSel = q & 1;
  bool hiTap = (q >= 2);
  #pragma unroll
  for (int m = 0; m < 5; m++){
    const int ta = 2*m, tb = (2*m + 1 > 8) ? 8 : (2*m + 1);
    int dy = (hiTap ? tb/3 : ta/3) - 1;
    int dx = (hiTap ? tb%3 : ta%3) - 1;
    int yy = y + dy * 4;
    int xx = x0 + col + dx * 4;
    U4B a;
    if (EDGE){
      bool valid = ((unsigned)yy < HH) && ((unsigned)xx < WW);
      a.u = make_uint4(0u, 0u, 0u, 0u);
      if (valid) a.u = hin[(((unsigned)((b << 18) | (yy << 9) | xx)) << 1) | (unsigned)chSel];
    } else {
      a.u = hin[(((unsigned)((b << 18) | (yy << 9) | xx)) << 1) | (unsigned)chSel];
    }
    U4B bb; bb.u = wfrag[m];
    cc = __builtin_amdgcn_mfma_f32_16x16x32_bf16(bb.h, a.h, cc, 0, 0, 0);
  }
  return cc;
}

// ======== kernel 4: conv3 (dil 4, MFMA) + BN/ReLU + w4 MFMA + sigmoid + enhance ========
// Per-wave LDS: kern rows, 64 px x 104 B (52 shorts; dword stride 26 -> conflict-free
// writes (banks 8q ^ col/2 = 32 distinct) and conflict-free b64 reads).
__global__ __launch_bounds__(256) void k_conv3m(const uint4* __restrict__ h2,
                                                const float* __restrict__ C,
                                                const unsigned* __restrict__ wsB3,
                                                const uint4* __restrict__ wsB4,
                                                const float* __restrict__ xal,
                                                float* __restrict__ out){
  __shared__ uint2 LB[4][832];               // 4 x 6656 B = 26624 B / block
  int lane = threadIdx.x & 63, wv = threadIdx.x >> 6;
  char* myL = (char*)LB[wv];
  unsigned short* Lk = (unsigned short*)myL;            // kern rows, 52 shorts stride
  int w = blockIdx.x * 4 + wv;
  int base = w << 6;
  int b = base >> 18, rem = base & (HWSZ - 1);
  int y = rem >> 9, wx = rem & 511;
  uint4 wfrag[5];
  #pragma unroll
  for (int m = 0; m < 5; m++) wfrag[m] = ((const uint4*)wsB3)[m*64 + lane];
  uint4 bw[3];
  #pragma unroll
  for (int c = 0; c < 3; c++) bw[c] = wsB4[c*64 + lane];
  int col = lane & 15, q = lane >> 4;
  float4 sc = *(const float4*)&C[320 + q*4];
  float4 bi = *(const float4*)&C[336 + q*4];
  float cb = C[242];                                    // bias
  int src0 = col + q*32;                                // h3 shuffle sources
  int src1 = src0 + 16;
  bool yIn = (y >= 4) && (y < 508);

  #pragma unroll
  for (int g = 0; g < 4; g++){
    int x0 = wx + g*16;
    // ---- stage 1: conv3 (C: col=px, row=ch) + BN + ReLU, packed in-register ----
    f32x4 cc = {0.f, 0.f, 0.f, 0.f};
    bool fast = yIn && (x0 >= 4) && (x0 <= 492);        // wave-uniform branch
    if (fast) cc = convW4<false>(h2, wfrag, b, y, x0, col, q, cc);
    else      cc = convW4<true >(h2, wfrag, b, y, x0, col, q, cc);
    float v0 = fmaxf(0.f, fmaf(cc[0], sc.x, bi.x));
    float v1 = fmaxf(0.f, fmaf(cc[1], sc.y, bi.y));
    float v2 = fmaxf(0.f, fmaf(cc[2], sc.z, bi.z));
    float v3 = fmaxf(0.f, fmaf(cc[3], sc.w, bi.w));
    int pk01 = (int)packpair(v0, v1);      // ch q*4, q*4+1 of pixel col
    int pk23 = (int)packpair(v2, v3);      // ch q*4+2, q*4+3

    // ---- C-layout -> A-layout via shuffles (q>=2 garbage is zeroed by wsB4 K-pad) ----
    U4B a;
    a.u.x = (unsigned)__shfl(pk01, src0);
    a.u.y = (unsigned)__shfl(pk23, src0);
    a.u.z = (unsigned)__shfl(pk01, src1);
    a.u.w = (unsigned)__shfl(pk23, src1);

    // ---- stage 2: w4 MFMA (K=16 padded to 32) + sigmoid -> kern LDS ----
    #pragma unroll
    for (int c = 0; c < 3; c++){
      f32x4 aw = {cb, cb, cb, cb};
      U4B bb; bb.u = bw[c];
      aw = __builtin_amdgcn_mfma_f32_16x16x32_bf16(a.h, bb.h, aw, 0, 0, 0);
      #pragma unroll
      for (int r = 0; r < 4; r++){
        float e  = __expf(-aw[r]);
        float rc = __builtin_amdgcn_rcpf(1.f + e);
        float kern = fmaf(10.f, rc, 0.1f);
        unsigned u = __float_as_uint(kern) + 0x8000u;
        Lk[(g*16 + q*4 + r)*52 + c*16 + col] = (unsigned short)(u >> 16);
      }
    }
  }

  // ---- stage 3: lane owns pixel (wx+lane); 45 kern x patch FMAs ----
  unsigned kvf[24];
  {
    const uint2* kp = (const uint2*)(myL + lane*104);
    #pragma unroll
    for (int jj = 0; jj < 12; jj++){
      uint2 u = kp[jj];
      kvf[2*jj] = u.x; kvf[2*jj+1] = u.y;
    }
  }
  int px = wx + lane;
  bool mxl = (px > 0), mxr = (px < 511), mym = (y > 0), myp = (y < 511);
  bool msk[9] = { mym&&mxl, mym, mym&&mxr,
                  mxl,      true, mxr,
                  myp&&mxl, myp, myp&&mxr };
  int rowm = mym ? -2048 : 0;
  int rowp = myp ?  2048 : 0;
  int loff = mxl ? -4 : 0;
  int roff = mxr ?  4 : 0;
  const char* base0 = (const char*)(xal + ((size_t)(b*TT) << 18) + (y << 9) + px);
  #pragma unroll
  for (int t = 0; t < TT; t++){
    const char* pc = base0 + (size_t)t * (HWSZ*4);
    const char* pm = pc + rowm;
    const char* pp = pc + rowp;
    float xv[9];
    xv[0] = *(const float*)(pm + loff);
    xv[1] = *(const float*)(pm);
    xv[2] = *(const float*)(pm + roff);
    xv[3] = *(const float*)(pc + loff);
    xv[4] = *(const float*)(pc);
    xv[5] = *(const float*)(pc + roff);
    xv[6] = *(const float*)(pp + loff);
    xv[7] = *(const float*)(pp);
    xv[8] = *(const float*)(pp + roff);
    float ov = 0.f;
    #pragma unroll
    for (int k = 0; k < 9; k++){
      int n = t*9 + k;
      unsigned u = kvf[n >> 1];
      float kf = (n & 1) ? bhi(u) : blo(u);
      float kern = msk[k] ? kf : 0.f;
      ov = fmaf(kern, xv[k], ov);
    }
    out[((size_t)(b*TT + t) << 18) + (y << 9) + px] = ov;
  }
}

extern "C" void kernel_launch(void* const* d_in, const int* in_sizes, int n_in,
                              void* d_out, int out_size, void* d_ws, size_t ws_size,
                              hipStream_t stream){
  const float* xal = (const float*)d_in[0];
  const float* rd  = (const float*)d_in[1];
  const float* w1  = (const float*)d_in[2];
  const float* g1  = (const float*)d_in[3];
  const float* b1  = (const float*)d_in[4];
  const float* rm1 = (const float*)d_in[5];
  const float* rv1 = (const float*)d_in[6];
  const float* w2  = (const float*)d_in[7];
  const float* g2  = (const float*)d_in[8];
  const float* b2  = (const float*)d_in[9];
  const float* rm2 = (const float*)d_in[10];
  const float* rv2 = (const float*)d_in[11];
  const float* w3  = (const float*)d_in[12];
  const float* g3  = (const float*)d_in[13];
  const float* b3  = (const float*)d_in[14];
  const float* rm3 = (const float*)d_in[15];
  const float* rv3 = (const float*)d_in[16];
  const float* w4  = (const float*)d_in[17];
  const float* bias= (const float*)d_in[18];
  float* out = (float*)d_out;

  char* ws = (char*)d_ws;
  float2*   partial = (float2*)ws;                    // 16 KB
  float*    cst   = (float*)(ws + 16384);             // 352 floats used
  unsigned* wsB2  = (unsigned*)(ws + 32768);          // 5 KB
  unsigned* wsB3  = (unsigned*)(ws + 40960);          // 5 KB
  uint4*    wsB4  = (uint4*)(ws + 49152);             // 3 KB
  float*    acc   = (float*)(ws + 65536);             // 8 MB
  char*     h2    = (char*)(ws + 65536 + (size_t)NPIX*4);                     // 64 MB

  k_acc<<<2048, 256, 0, stream>>>(rd, (float4*)acc, partial);
  k_prep<<<1, 256, 0, stream>>>(partial, w1, w2, w3,
                                g1, b1, rm1, rv1,
                                g2, b2, rm2, rv2,
                                g3, b3, rm3, rv3, w4, bias, cst, wsB2, wsB3, wsB4);
  k_conv12<<<4096, 256, 0, stream>>>(acc, cst, wsB2, (uint2*)h2);
  k_conv3m<<<NPIX/256, 256, 0, stream>>>((const uint4*)h2, cst, wsB3, wsB4, xal, out);
}